// Round 5
// baseline (1093.796 us; speedup 1.0000x reference)
//
#include <hip/hip_runtime.h>
#include <math.h>

typedef __bf16 bf16x8 __attribute__((ext_vector_type(8)));
typedef float  f32x4  __attribute__((ext_vector_type(4)));

__device__ __forceinline__ ushort f2bf(float f) {
  union { float f; unsigned u; } v; v.f = f;
  unsigned r = v.u + 0x7FFFu + ((v.u >> 16) & 1u);
  return (ushort)(r >> 16);
}
__device__ __forceinline__ float bf2f(ushort s) {
  union { unsigned u; float f; } v; v.u = ((unsigned)s) << 16;
  return v.f;
}

__device__ __forceinline__ void gload_lds16(const ushort* g, ushort* l) {
  __builtin_amdgcn_global_load_lds((const __attribute__((address_space(1))) void*)g,
                                   (__attribute__((address_space(3))) void*)l, 16, 0, 0);
}

// fast GELU (tanh form): h * sigmoid(1.5957691*h*(1+0.044715*h^2))
__device__ __forceinline__ float gelu_fast(float h) {
  float y = 1.5957691216057308f * h * (1.f + 0.044715f * h * h);
  float e = __expf(y);
  return h * e / (e + 1.f);
}

// ---------------- weight transpose + bf16 convert: W[K][N] -> WT[N][K] ----------------
__global__ void wtrans_kernel(const float* __restrict__ W, ushort* __restrict__ WT,
                              int K, int N) {
  int idx = blockIdx.x * 256 + threadIdx.x;
  if (idx >= K * N) return;
  int n = idx / K, k = idx - n * K;
  WT[idx] = f2bf(W[(size_t)k * N + n]);
}

// ---------------- LayerNorm (one wave per row of 384) ----------------
template<bool SHIFT, bool INBF16>
__global__ __launch_bounds__(256) void ln_kernel(const void* __restrict__ inp,
                                                 ushort* __restrict__ outp,
                                                 const float* __restrict__ gamma,
                                                 const float* __restrict__ beta) {
  const int lane = threadIdx.x & 63;
  const int row = blockIdx.x * 4 + (threadIdx.x >> 6);
  size_t src;
  if (SHIFT) {
    int b = row / 3136, rem = row - b * 3136;
    int win = rem / 49, n = rem - win * 49;
    int wh = win >> 3, ww = win & 7;
    int i = n / 7, j = n - (n / 7) * 7;
    int h = wh * 7 + i + 3; if (h >= 56) h -= 56;
    int w = ww * 7 + j + 3; if (w >= 56) w -= 56;
    src = ((size_t)b * 3136 + h * 56 + w) * 384;
  } else {
    src = (size_t)row * 384;
  }
  float xv[6];
  float sum = 0.f, sq = 0.f;
#pragma unroll
  for (int t = 0; t < 6; t++) {
    int c = lane + t * 64;
    float f;
    if (INBF16) f = bf2f(((const ushort*)inp)[src + c]);
    else        f = ((const float*)inp)[src + c];
    xv[t] = f; sum += f; sq += f * f;
  }
#pragma unroll
  for (int o = 32; o; o >>= 1) { sum += __shfl_xor(sum, o); sq += __shfl_xor(sq, o); }
  float mean = sum * (1.f / 384.f);
  float var  = sq * (1.f / 384.f) - mean * mean;
  float inv  = rsqrtf(var + 1e-5f);
#pragma unroll
  for (int t = 0; t < 6; t++) {
    int c = lane + t * 64;
    outp[(size_t)row * 384 + c] = f2bf((xv[t] - mean) * inv * gamma[c] + beta[c]);
  }
}

// ---------------- bf16 MFMA GEMM: C[M][N] = A[M][K] * BT[N][K]^T + bias ----------------
// 3-buffer LDS, 2-deep global_load_lds prefetch, counted vmcnt(4), raw s_barrier.
#define EPI_QKV  0
#define EPI_PROJ 1
#define EPI_MLP1 2
#define EPI_MLP2 3

template<int EPI>
__global__ __launch_bounds__(256) void gemm_kernel(
    const ushort* __restrict__ A, const ushort* __restrict__ BT,
    const float* __restrict__ bias, void* __restrict__ Cout,
    const void* __restrict__ extra, int M, int N, int K, int nbn, int cpx) {
  __shared__ ushort As[3][128 * 32];
  __shared__ ushort Bs[3][128 * 32];
  const int tid = threadIdx.x;
  // bijective XCD swizzle (nwg % 8 == 0, verified host-side)
  const int flat = blockIdx.x;
  const int wg = (flat & 7) * cpx + (flat >> 3);
  const int bm = wg / nbn, bn = wg - bm * nbn;
  const int m0 = bm * 128, n0 = bn * 128;
  const int lane = tid & 63, wave = tid >> 6;
  const int wr = (wave >> 1) * 64, wc = (wave & 1) * 64;
  const int fr = lane & 15, fq = lane >> 4;
  f32x4 acc[4][4] = {};

  // staging: wave stages rows [wave*32, wave*32+32) (linear lane order)
  const size_t a_off = (size_t)(m0 + wave * 32 + (lane >> 2)) * K + (lane & 3) * 8;
  const size_t b_off = (size_t)(n0 + wave * 32 + (lane >> 2)) * K + (lane & 3) * 8;

#define STAGE(c, kt_) do {                                        \
    const ushort* ga = A  + a_off + (kt_);                        \
    const ushort* gb = BT + b_off + (kt_);                        \
    gload_lds16(ga,          &As[c][wave * 1024]);                \
    gload_lds16(ga + 16 * K, &As[c][wave * 1024 + 512]);          \
    gload_lds16(gb,          &Bs[c][wave * 1024]);                \
    gload_lds16(gb + 16 * K, &Bs[c][wave * 1024 + 512]);          \
  } while (0)

  const int NT = K >> 5;
  STAGE(0, 0);
  STAGE(1, 32);
  asm volatile("s_waitcnt vmcnt(4) lgkmcnt(0)" ::: "memory");
  __builtin_amdgcn_s_barrier();
  __builtin_amdgcn_sched_barrier(0);

  int cur = 0;
  for (int t = 0; t < NT; ++t) {
    if (t + 2 < NT) {
      int nx2 = cur + 2; if (nx2 >= 3) nx2 -= 3;
      STAGE(nx2, (t + 2) * 32);
    }
    bf16x8 a[4], b[4];
#pragma unroll
    for (int i = 0; i < 4; i++)
      a[i] = *(const bf16x8*)&As[cur][(wr + i * 16 + fr) * 32 + fq * 8];
#pragma unroll
    for (int i = 0; i < 4; i++)
      b[i] = *(const bf16x8*)&Bs[cur][(wc + i * 16 + fr) * 32 + fq * 8];
#pragma unroll
    for (int i = 0; i < 4; i++)
#pragma unroll
      for (int j = 0; j < 4; j++)
        acc[i][j] = __builtin_amdgcn_mfma_f32_16x16x32_bf16(a[i], b[j], acc[i][j], 0, 0, 0);
    if (t + 1 < NT) {
      if (t + 2 < NT) asm volatile("s_waitcnt vmcnt(4) lgkmcnt(0)" ::: "memory");
      else            asm volatile("s_waitcnt vmcnt(0) lgkmcnt(0)" ::: "memory");
      __builtin_amdgcn_s_barrier();
      __builtin_amdgcn_sched_barrier(0);
    }
    cur += 1; if (cur >= 3) cur -= 3;
  }
#undef STAGE

#pragma unroll
  for (int i = 0; i < 4; i++) {
#pragma unroll
    for (int r = 0; r < 4; r++) {
      const int m = m0 + wr + i * 16 + fq * 4 + r;
      size_t rowbase;
      if constexpr (EPI == EPI_PROJ) {
        int b_ = m / 3136, rem = m - b_ * 3136;
        int win = rem / 49, nn = rem - win * 49;
        int wh = win >> 3, ww = win & 7;
        int ii = nn / 7, jj = nn - (nn / 7) * 7;
        int h = wh * 7 + ii + 3; if (h >= 56) h -= 56;
        int w = ww * 7 + jj + 3; if (w >= 56) w -= 56;
        rowbase = ((size_t)b_ * 3136 + h * 56 + w) * 384;
      } else {
        rowbase = (size_t)m * N;
      }
#pragma unroll
      for (int j = 0; j < 4; j++) {
        const int col = n0 + wc + j * 16 + fr;
        float val = acc[i][j][r] + bias[col];
        if constexpr (EPI == EPI_QKV) {
          ((ushort*)Cout)[rowbase + col] = f2bf(val);
        } else if constexpr (EPI == EPI_PROJ) {
          // x1 (bf16 trunk) = x (fp32 input) + proj out, scattered to unshifted pos
          ((ushort*)Cout)[rowbase + col] =
              f2bf(((const float*)extra)[rowbase + col] + val);
        } else if constexpr (EPI == EPI_MLP1) {
          ((ushort*)Cout)[rowbase + col] = f2bf(gelu_fast(val));
        } else { // MLP2: d_out (fp32) = mlp2 out + x1 (bf16)
          ((float*)Cout)[rowbase + col] =
              val + bf2f(((const ushort*)extra)[rowbase + col]);
        }
      }
    }
  }
}

// ---------------- windowed attention: streaming softmax, 2 waves/block ----------------
__global__ __launch_bounds__(128) void attn_kernel(
    const ushort* __restrict__ qkv, const float* __restrict__ bias_table,
    ushort* __restrict__ outp) {
  __shared__ float ksv[2][49 * 64];   // per wave: row m -> [K 0..31 | V 32..63]
  __shared__ float btab[2][169];
  __shared__ char  rgn[2][52];
  const int wave = threadIdx.x >> 6, lane = threadIdx.x & 63;
  const int gw = blockIdx.x * 2 + wave;        // 0..24575
  const int bw = gw / 12, head = gw - bw * 12;
  const ushort* base = qkv + (size_t)bw * 49 * 1152 + head * 32;

  for (int t = lane; t < 784; t += 64) {
    int row = t >> 4;
    int c0  = (t & 15) * 4;
    int src_c = (c0 < 32) ? (384 + c0) : (736 + c0);
    ushort4 u = *(const ushort4*)(base + (size_t)row * 1152 + src_c);
    float4 f = make_float4(bf2f(u.x), bf2f(u.y), bf2f(u.z), bf2f(u.w));
    *(float4*)&ksv[wave][row * 64 + c0] = f;
  }
  for (int t = lane; t < 169; t += 64) btab[wave][t] = bias_table[t * 12 + head];
  {
    int win = bw & 63, wh = win >> 3, ww = win & 7;
    if (lane < 49) {
      int i = lane / 7, j = lane - (lane / 7) * 7;
      int hs = wh * 7 + i, wsf = ww * 7 + j;
      int bh = (hs < 49) ? 0 : (hs < 53 ? 1 : 2);
      int bv = (wsf < 49) ? 0 : (wsf < 53 ? 1 : 2);
      rgn[wave][lane] = (char)(bh * 3 + bv);
    }
  }
  __syncthreads();

  const int n = (lane < 49) ? lane : 48;
  float4 q4[8];
  {
    const ushort* qp = base + (size_t)n * 1152;
#pragma unroll
    for (int t = 0; t < 8; t++) {
      ushort4 u = *(const ushort4*)(qp + t * 4);
      q4[t] = make_float4(bf2f(u.x) * 0.17677669529663689f, bf2f(u.y) * 0.17677669529663689f,
                          bf2f(u.z) * 0.17677669529663689f, bf2f(u.w) * 0.17677669529663689f);
    }
  }
  const int rn = rgn[wave][n];
  const int i_n = n / 7, j_n = n - (n / 7) * 7;
  const float* bt = &btab[wave][(i_n + 6) * 13 + (j_n + 6)];
  const float* kb = &ksv[wave][0];

  float4 o4[8] = {};
  float sum = 0.f;
  for (int im = 0; im < 7; im++) {
#pragma unroll
    for (int jm = 0; jm < 7; jm++) {
      const int m_ = im * 7 + jm;
      const float4* kk = (const float4*)(kb + m_ * 64);
      float4 d = {};
#pragma unroll
      for (int t = 0; t < 8; t++) {
        float4 kv = kk[t];
        d.x += q4[t].x * kv.x; d.y += q4[t].y * kv.y;
        d.z += q4[t].z * kv.z; d.w += q4[t].w * kv.w;
      }
      float s = (d.x + d.y) + (d.z + d.w) + bt[-im * 13 - jm]
              + ((rn == rgn[wave][m_]) ? 0.f : -100.f);
      float e = __expf(s);
      sum += e;
      const float4* vv = (const float4*)(kb + m_ * 64 + 32);
#pragma unroll
      for (int t = 0; t < 8; t++) {
        float4 w = vv[t];
        o4[t].x += e * w.x; o4[t].y += e * w.y;
        o4[t].z += e * w.z; o4[t].w += e * w.w;
      }
    }
  }
  if (lane < 49) {
    float inv = 1.f / sum;
    ushort* op = outp + (size_t)(bw * 49 + n) * 384 + head * 32;
#pragma unroll
    for (int t = 0; t < 8; t++) {
      ushort4 u;
      u.x = f2bf(o4[t].x * inv); u.y = f2bf(o4[t].y * inv);
      u.z = f2bf(o4[t].z * inv); u.w = f2bf(o4[t].w * inv);
      *(ushort4*)(op + t * 4) = u;
    }
  }
}

extern "C" void kernel_launch(void* const* d_in, const int* in_sizes, int n_in,
                              void* d_out, int out_size, void* d_ws, size_t ws_size,
                              hipStream_t stream) {
  (void)in_sizes; (void)n_in; (void)out_size; (void)ws_size;
  const float* x      = (const float*)d_in[0];
  const float* W_qkv  = (const float*)d_in[1];
  const float* b_qkv  = (const float*)d_in[2];
  const float* W_proj = (const float*)d_in[3];
  const float* b_proj = (const float*)d_in[4];
  const float* btab   = (const float*)d_in[5];
  const float* gamma1 = (const float*)d_in[6];
  const float* beta1  = (const float*)d_in[7];
  const float* gamma2 = (const float*)d_in[8];
  const float* beta2  = (const float*)d_in[9];
  const float* W_mlp1 = (const float*)d_in[10];
  const float* b_mlp1 = (const float*)d_in[11];
  const float* W_mlp2 = (const float*)d_in[12];
  const float* b_mlp2 = (const float*)d_in[13];

  const int M = 100352;  // 32 * 3136 token rows

  char* ws = (char*)d_ws;
  ushort* WqkvT  = (ushort*)ws; ws += (size_t)1152 * 384 * 2;
  ushort* WprojT = (ushort*)ws; ws += (size_t)384 * 384 * 2;
  ushort* Wm1T   = (ushort*)ws; ws += (size_t)1536 * 384 * 2;
  ushort* Wm2T   = (ushort*)ws; ws += (size_t)384 * 1536 * 2;
  ushort* x1     = (ushort*)ws; ws += (size_t)M * 384 * 2;   // bf16 residual trunk
  ushort* h2     = (ushort*)ws; ws += (size_t)M * 384 * 2;
  ushort* bufB   = (ushort*)ws;                               // overlay region
  ushort* xw     = bufB;                                      // [M][384]
  ushort* qkv    = bufB + (size_t)M * 384;                    // [M][1152]
  ushort* attn_o = bufB;                                      // [M][384]  (over xw)
  ushort* g      = bufB;                                      // [M][1536] (over all)

  wtrans_kernel<<<(384 * 1152 + 255) / 256, 256, 0, stream>>>(W_qkv,  WqkvT,  384, 1152);
  wtrans_kernel<<<(384 * 384  + 255) / 256, 256, 0, stream>>>(W_proj, WprojT, 384, 384);
  wtrans_kernel<<<(384 * 1536 + 255) / 256, 256, 0, stream>>>(W_mlp1, Wm1T,   384, 1536);
  wtrans_kernel<<<(1536 * 384 + 255) / 256, 256, 0, stream>>>(W_mlp2, Wm2T,   1536, 384);

  ln_kernel<true,  false><<<M / 4, 256, 0, stream>>>(x, xw, gamma1, beta1);

  {
    int nbn = 1152 / 128, nwg = (M / 128) * nbn;
    gemm_kernel<EPI_QKV ><<<nwg, 256, 0, stream>>>(xw, WqkvT, b_qkv, qkv, nullptr, M, 1152, 384, nbn, nwg / 8);
  }
  attn_kernel<<<12288, 128, 0, stream>>>(qkv, btab, attn_o);
  {
    int nbn = 384 / 128, nwg = (M / 128) * nbn;
    gemm_kernel<EPI_PROJ><<<nwg, 256, 0, stream>>>(attn_o, WprojT, b_proj, x1, x, M, 384, 384, nbn, nwg / 8);
  }
  ln_kernel<false, true><<<M / 4, 256, 0, stream>>>(x1, h2, gamma2, beta2);
  {
    int nbn = 1536 / 128, nwg = (M / 128) * nbn;
    gemm_kernel<EPI_MLP1><<<nwg, 256, 0, stream>>>(h2, Wm1T, b_mlp1, g, nullptr, M, 1536, 384, nbn, nwg / 8);
  }
  {
    int nbn = 384 / 128, nwg = (M / 128) * nbn;
    gemm_kernel<EPI_MLP2><<<nwg, 256, 0, stream>>>(g, Wm2T, b_mlp2, d_out, x1, M, 384, 1536, nbn, nwg / 8);
  }
}

// Round 6
// 1025.705 us; speedup vs baseline: 1.0664x; 1.0664x over previous
//
#include <hip/hip_runtime.h>
#include <math.h>

typedef __bf16 bf16x8 __attribute__((ext_vector_type(8)));
typedef float  f32x4  __attribute__((ext_vector_type(4)));

__device__ __forceinline__ ushort f2bf(float f) {
  union { float f; unsigned u; } v; v.f = f;
  unsigned r = v.u + 0x7FFFu + ((v.u >> 16) & 1u);
  return (ushort)(r >> 16);
}
__device__ __forceinline__ float bf2f(ushort s) {
  union { unsigned u; float f; } v; v.u = ((unsigned)s) << 16;
  return v.f;
}

__device__ __forceinline__ void gload_lds16(const ushort* g, ushort* l) {
  __builtin_amdgcn_global_load_lds((const __attribute__((address_space(1))) void*)g,
                                   (__attribute__((address_space(3))) void*)l, 16, 0, 0);
}

// fast GELU (tanh form)
__device__ __forceinline__ float gelu_fast(float h) {
  float y = 1.5957691216057308f * h * (1.f + 0.044715f * h * h);
  float e = __expf(y);
  return h * e / (e + 1.f);
}

// ---------------- weight transpose + bf16 convert: W[K][N] -> WT[N][K] ----------------
__global__ void wtrans_kernel(const float* __restrict__ W, ushort* __restrict__ WT,
                              int K, int N) {
  int idx = blockIdx.x * 256 + threadIdx.x;
  if (idx >= K * N) return;
  int n = idx / K, k = idx - n * K;
  WT[idx] = f2bf(W[(size_t)k * N + n]);
}

// ---------------- LayerNorm (one wave per row of 384) ----------------
template<bool SHIFT, bool INBF16>
__global__ __launch_bounds__(256) void ln_kernel(const void* __restrict__ inp,
                                                 ushort* __restrict__ outp,
                                                 const float* __restrict__ gamma,
                                                 const float* __restrict__ beta) {
  const int lane = threadIdx.x & 63;
  const int row = blockIdx.x * 4 + (threadIdx.x >> 6);
  size_t src;
  if (SHIFT) {
    int b = row / 3136, rem = row - b * 3136;
    int win = rem / 49, n = rem - win * 49;
    int wh = win >> 3, ww = win & 7;
    int i = n / 7, j = n - (n / 7) * 7;
    int h = wh * 7 + i + 3; if (h >= 56) h -= 56;
    int w = ww * 7 + j + 3; if (w >= 56) w -= 56;
    src = ((size_t)b * 3136 + h * 56 + w) * 384;
  } else {
    src = (size_t)row * 384;
  }
  float xv[6];
  float sum = 0.f, sq = 0.f;
#pragma unroll
  for (int t = 0; t < 6; t++) {
    int c = lane + t * 64;
    float f;
    if (INBF16) f = bf2f(((const ushort*)inp)[src + c]);
    else        f = ((const float*)inp)[src + c];
    xv[t] = f; sum += f; sq += f * f;
  }
#pragma unroll
  for (int o = 32; o; o >>= 1) { sum += __shfl_xor(sum, o); sq += __shfl_xor(sq, o); }
  float mean = sum * (1.f / 384.f);
  float var  = sq * (1.f / 384.f) - mean * mean;
  float inv  = rsqrtf(var + 1e-5f);
#pragma unroll
  for (int t = 0; t < 6; t++) {
    int c = lane + t * 64;
    outp[(size_t)row * 384 + c] = f2bf((xv[t] - mean) * inv * gamma[c] + beta[c]);
  }
}

// ---------------- bf16 MFMA GEMM: C[M][N] = A[M][K] * BT[N][K]^T + bias ----------------
// 256x128 block, 4 waves of 128x64 (8x4 frags). 3-buffer LDS, 2-deep prefetch,
// counted vmcnt(6), raw s_barrier. LDS k-slot swizzle: slot ^= (row>>1)&3 on
// both DMA-source and fragment-read sides (involution) -> 2-way residual (free).
#define EPI_QKV  0
#define EPI_PROJ 1
#define EPI_MLP1 2
#define EPI_MLP2 3

template<int EPI>
__global__ __launch_bounds__(256, 2) void gemm_kernel(
    const ushort* __restrict__ A, const ushort* __restrict__ BT,
    const float* __restrict__ bias, void* __restrict__ Cout,
    const void* __restrict__ extra, int M, int N, int K, int nbn, int cpx) {
  __shared__ ushort As[3][256 * 32];
  __shared__ ushort Bs[3][128 * 32];
  const int tid = threadIdx.x;
  // bijective XCD swizzle (nwg % 8 == 0, verified host-side)
  const int flat = blockIdx.x;
  const int wg = (flat & 7) * cpx + (flat >> 3);
  const int bm = wg / nbn, bn = wg - bm * nbn;
  const int m0 = bm * 256, n0 = bn * 128;
  const int lane = tid & 63, wave = tid >> 6;
  const int wr = (wave >> 1) * 128, wc = (wave & 1) * 64;
  const int fr = lane & 15, fq = lane >> 4;
  const int fqs = (fq ^ ((fr >> 1) & 3)) * 8;   // swizzled k-slot byte/8 offset (lane-const)
  f32x4 acc[8][4] = {};

  // staging: wave stages A rows [wave*64, +64) (4 chunks), B rows [wave*32, +32) (2 chunks)
  const int rIC    = lane >> 2;                                  // row within 16-row chunk
  const int srccol = (((lane & 3) ^ ((lane >> 3) & 3)) * 8);     // swizzled source k-slot
  const size_t a_base = (size_t)(m0 + wave * 64 + rIC) * K + srccol;
  const size_t b_base = (size_t)(n0 + wave * 32 + rIC) * K + srccol;

#define STAGE(c, kt_) do {                                        \
    const ushort* ga = A  + a_base + (kt_);                       \
    const ushort* gb = BT + b_base + (kt_);                       \
    ushort* la = &As[c][wave * 64 * 32];                          \
    ushort* lb = &Bs[c][wave * 32 * 32];                          \
    gload_lds16(ga,          la);                                 \
    gload_lds16(ga + 16 * K, la + 16 * 32);                       \
    gload_lds16(ga + 32 * K, la + 32 * 32);                       \
    gload_lds16(ga + 48 * K, la + 48 * 32);                       \
    gload_lds16(gb,          lb);                                 \
    gload_lds16(gb + 16 * K, lb + 16 * 32);                       \
  } while (0)

  const int NT = K >> 5;
  STAGE(0, 0);
  STAGE(1, 32);
  asm volatile("s_waitcnt vmcnt(6) lgkmcnt(0)" ::: "memory");
  __builtin_amdgcn_s_barrier();
  __builtin_amdgcn_sched_barrier(0);

  int cur = 0;
  for (int t = 0; t < NT; ++t) {
    if (t + 2 < NT) {
      int nx2 = cur + 2; if (nx2 >= 3) nx2 -= 3;
      STAGE(nx2, (t + 2) * 32);
    }
    bf16x8 a[8], b[4];
#pragma unroll
    for (int i = 0; i < 8; i++)
      a[i] = *(const bf16x8*)&As[cur][(wr + i * 16 + fr) * 32 + fqs];
#pragma unroll
    for (int j = 0; j < 4; j++)
      b[j] = *(const bf16x8*)&Bs[cur][(wc + j * 16 + fr) * 32 + fqs];
#pragma unroll
    for (int i = 0; i < 8; i++)
#pragma unroll
      for (int j = 0; j < 4; j++)
        acc[i][j] = __builtin_amdgcn_mfma_f32_16x16x32_bf16(a[i], b[j], acc[i][j], 0, 0, 0);
    if (t + 1 < NT) {
      if (t + 2 < NT) asm volatile("s_waitcnt vmcnt(6) lgkmcnt(0)" ::: "memory");
      else            asm volatile("s_waitcnt vmcnt(0) lgkmcnt(0)" ::: "memory");
      __builtin_amdgcn_s_barrier();
      __builtin_amdgcn_sched_barrier(0);
    }
    cur += 1; if (cur >= 3) cur -= 3;
  }
#undef STAGE

#pragma unroll
  for (int i = 0; i < 8; i++) {
#pragma unroll
    for (int r = 0; r < 4; r++) {
      const int m = m0 + wr + i * 16 + fq * 4 + r;
      size_t rowbase;
      if constexpr (EPI == EPI_PROJ) {
        int b_ = m / 3136, rem = m - b_ * 3136;
        int win = rem / 49, nn = rem - win * 49;
        int wh = win >> 3, ww = win & 7;
        int ii = nn / 7, jj = nn - (nn / 7) * 7;
        int h = wh * 7 + ii + 3; if (h >= 56) h -= 56;
        int w = ww * 7 + jj + 3; if (w >= 56) w -= 56;
        rowbase = ((size_t)b_ * 3136 + h * 56 + w) * 384;
      } else {
        rowbase = (size_t)m * N;
      }
#pragma unroll
      for (int j = 0; j < 4; j++) {
        const int col = n0 + wc + j * 16 + fr;
        float val = acc[i][j][r] + bias[col];
        if constexpr (EPI == EPI_QKV) {
          ((ushort*)Cout)[rowbase + col] = f2bf(val);
        } else if constexpr (EPI == EPI_PROJ) {
          ((ushort*)Cout)[rowbase + col] =
              f2bf(((const float*)extra)[rowbase + col] + val);
        } else if constexpr (EPI == EPI_MLP1) {
          ((ushort*)Cout)[rowbase + col] = f2bf(gelu_fast(val));
        } else { // MLP2: d_out (fp32) = mlp2 out + x1 (bf16)
          ((float*)Cout)[rowbase + col] =
              val + bf2f(((const ushort*)extra)[rowbase + col]);
        }
      }
    }
  }
}

// ---------------- windowed attention: streaming softmax, 2 waves/block ----------------
__global__ __launch_bounds__(128) void attn_kernel(
    const ushort* __restrict__ qkv, const float* __restrict__ bias_table,
    ushort* __restrict__ outp) {
  __shared__ float ksv[2][49 * 64];   // per wave: row m -> [K 0..31 | V 32..63]
  __shared__ float btab[2][169];
  __shared__ char  rgn[2][52];
  const int wave = threadIdx.x >> 6, lane = threadIdx.x & 63;
  const int gw = blockIdx.x * 2 + wave;        // 0..24575
  const int bw = gw / 12, head = gw - bw * 12;
  const ushort* base = qkv + (size_t)bw * 49 * 1152 + head * 32;

  for (int t = lane; t < 784; t += 64) {
    int row = t >> 4;
    int c0  = (t & 15) * 4;
    int src_c = (c0 < 32) ? (384 + c0) : (736 + c0);
    ushort4 u = *(const ushort4*)(base + (size_t)row * 1152 + src_c);
    float4 f = make_float4(bf2f(u.x), bf2f(u.y), bf2f(u.z), bf2f(u.w));
    *(float4*)&ksv[wave][row * 64 + c0] = f;
  }
  for (int t = lane; t < 169; t += 64) btab[wave][t] = bias_table[t * 12 + head];
  {
    int win = bw & 63, wh = win >> 3, ww = win & 7;
    if (lane < 49) {
      int i = lane / 7, j = lane - (lane / 7) * 7;
      int hs = wh * 7 + i, wsf = ww * 7 + j;
      int bh = (hs < 49) ? 0 : (hs < 53 ? 1 : 2);
      int bv = (wsf < 49) ? 0 : (wsf < 53 ? 1 : 2);
      rgn[wave][lane] = (char)(bh * 3 + bv);
    }
  }
  __syncthreads();

  const int n = (lane < 49) ? lane : 48;
  float4 q4[8];
  {
    const ushort* qp = base + (size_t)n * 1152;
#pragma unroll
    for (int t = 0; t < 8; t++) {
      ushort4 u = *(const ushort4*)(qp + t * 4);
      q4[t] = make_float4(bf2f(u.x) * 0.17677669529663689f, bf2f(u.y) * 0.17677669529663689f,
                          bf2f(u.z) * 0.17677669529663689f, bf2f(u.w) * 0.17677669529663689f);
    }
  }
  const int rn = rgn[wave][n];
  const int i_n = n / 7, j_n = n - (n / 7) * 7;
  const float* bt = &btab[wave][(i_n + 6) * 13 + (j_n + 6)];
  const float* kb = &ksv[wave][0];

  float4 o4[8] = {};
  float sum = 0.f;
  for (int im = 0; im < 7; im++) {
#pragma unroll
    for (int jm = 0; jm < 7; jm++) {
      const int m_ = im * 7 + jm;
      const float4* kk = (const float4*)(kb + m_ * 64);
      float4 d = {};
#pragma unroll
      for (int t = 0; t < 8; t++) {
        float4 kv = kk[t];
        d.x += q4[t].x * kv.x; d.y += q4[t].y * kv.y;
        d.z += q4[t].z * kv.z; d.w += q4[t].w * kv.w;
      }
      float s = (d.x + d.y) + (d.z + d.w) + bt[-im * 13 - jm]
              + ((rn == rgn[wave][m_]) ? 0.f : -100.f);
      float e = __expf(s);
      sum += e;
      const float4* vv = (const float4*)(kb + m_ * 64 + 32);
#pragma unroll
      for (int t = 0; t < 8; t++) {
        float4 w = vv[t];
        o4[t].x += e * w.x; o4[t].y += e * w.y;
        o4[t].z += e * w.z; o4[t].w += e * w.w;
      }
    }
  }
  if (lane < 49) {
    float inv = 1.f / sum;
    ushort* op = outp + (size_t)(bw * 49 + n) * 384 + head * 32;
#pragma unroll
    for (int t = 0; t < 8; t++) {
      ushort4 u;
      u.x = f2bf(o4[t].x * inv); u.y = f2bf(o4[t].y * inv);
      u.z = f2bf(o4[t].z * inv); u.w = f2bf(o4[t].w * inv);
      *(ushort4*)(op + t * 4) = u;
    }
  }
}

extern "C" void kernel_launch(void* const* d_in, const int* in_sizes, int n_in,
                              void* d_out, int out_size, void* d_ws, size_t ws_size,
                              hipStream_t stream) {
  (void)in_sizes; (void)n_in; (void)out_size; (void)ws_size;
  const float* x      = (const float*)d_in[0];
  const float* W_qkv  = (const float*)d_in[1];
  const float* b_qkv  = (const float*)d_in[2];
  const float* W_proj = (const float*)d_in[3];
  const float* b_proj = (const float*)d_in[4];
  const float* btab   = (const float*)d_in[5];
  const float* gamma1 = (const float*)d_in[6];
  const float* beta1  = (const float*)d_in[7];
  const float* gamma2 = (const float*)d_in[8];
  const float* beta2  = (const float*)d_in[9];
  const float* W_mlp1 = (const float*)d_in[10];
  const float* b_mlp1 = (const float*)d_in[11];
  const float* W_mlp2 = (const float*)d_in[12];
  const float* b_mlp2 = (const float*)d_in[13];

  const int M = 100352;  // 32 * 3136 token rows

  char* ws = (char*)d_ws;
  ushort* WqkvT  = (ushort*)ws; ws += (size_t)1152 * 384 * 2;
  ushort* WprojT = (ushort*)ws; ws += (size_t)384 * 384 * 2;
  ushort* Wm1T   = (ushort*)ws; ws += (size_t)1536 * 384 * 2;
  ushort* Wm2T   = (ushort*)ws; ws += (size_t)384 * 1536 * 2;
  ushort* x1     = (ushort*)ws; ws += (size_t)M * 384 * 2;   // bf16 residual trunk
  ushort* h2     = (ushort*)ws; ws += (size_t)M * 384 * 2;
  ushort* bufB   = (ushort*)ws;                               // overlay region
  ushort* xw     = bufB;                                      // [M][384]
  ushort* qkv    = bufB + (size_t)M * 384;                    // [M][1152]
  ushort* attn_o = bufB;                                      // [M][384]  (over xw)
  ushort* g      = bufB;                                      // [M][1536] (over all)

  wtrans_kernel<<<(384 * 1152 + 255) / 256, 256, 0, stream>>>(W_qkv,  WqkvT,  384, 1152);
  wtrans_kernel<<<(384 * 384  + 255) / 256, 256, 0, stream>>>(W_proj, WprojT, 384, 384);
  wtrans_kernel<<<(384 * 1536 + 255) / 256, 256, 0, stream>>>(W_mlp1, Wm1T,   384, 1536);
  wtrans_kernel<<<(1536 * 384 + 255) / 256, 256, 0, stream>>>(W_mlp2, Wm2T,   1536, 384);

  ln_kernel<true,  false><<<M / 4, 256, 0, stream>>>(x, xw, gamma1, beta1);

  {
    int nbn = 1152 / 128, nwg = (M / 256) * nbn;
    gemm_kernel<EPI_QKV ><<<nwg, 256, 0, stream>>>(xw, WqkvT, b_qkv, qkv, nullptr, M, 1152, 384, nbn, nwg / 8);
  }
  attn_kernel<<<12288, 128, 0, stream>>>(qkv, btab, attn_o);
  {
    int nbn = 384 / 128, nwg = (M / 256) * nbn;
    gemm_kernel<EPI_PROJ><<<nwg, 256, 0, stream>>>(attn_o, WprojT, b_proj, x1, x, M, 384, 384, nbn, nwg / 8);
  }
  ln_kernel<false, true><<<M / 4, 256, 0, stream>>>(x1, h2, gamma2, beta2);
  {
    int nbn = 1536 / 128, nwg = (M / 256) * nbn;
    gemm_kernel<EPI_MLP1><<<nwg, 256, 0, stream>>>(h2, Wm1T, b_mlp1, g, nullptr, M, 1536, 384, nbn, nwg / 8);
  }
  {
    int nbn = 384 / 128, nwg = (M / 256) * nbn;
    gemm_kernel<EPI_MLP2><<<nwg, 256, 0, stream>>>(g, Wm2T, b_mlp2, d_out, x1, M, 384, 1536, nbn, nwg / 8);
  }
}

// Round 7
// 983.915 us; speedup vs baseline: 1.1117x; 1.0425x over previous
//
#include <hip/hip_runtime.h>
#include <math.h>

typedef __bf16 bf16x8 __attribute__((ext_vector_type(8)));
typedef float  f32x4  __attribute__((ext_vector_type(4)));

__device__ __forceinline__ ushort f2bf(float f) {
  union { float f; unsigned u; } v; v.f = f;
  unsigned r = v.u + 0x7FFFu + ((v.u >> 16) & 1u);
  return (ushort)(r >> 16);
}
__device__ __forceinline__ float bf2f(ushort s) {
  union { unsigned u; float f; } v; v.u = ((unsigned)s) << 16;
  return v.f;
}

__device__ __forceinline__ void gload_lds16(const ushort* g, ushort* l) {
  __builtin_amdgcn_global_load_lds((const __attribute__((address_space(1))) void*)g,
                                   (__attribute__((address_space(3))) void*)l, 16, 0, 0);
}

// fast GELU: h * sigmoid(1.5957691*h*(1+0.044715*h^2)), sigmoid via v_rcp
__device__ __forceinline__ float gelu_fast(float h) {
  float y = 1.5957691216057308f * h * (1.f + 0.044715f * h * h);
  return h * __builtin_amdgcn_rcpf(1.f + __expf(-y));
}

// ---------------- weight transpose + bf16 convert: W[K][N] -> WT[N][K] ----------------
__global__ void wtrans_kernel(const float* __restrict__ W, ushort* __restrict__ WT,
                              int K, int N) {
  int idx = blockIdx.x * 256 + threadIdx.x;
  if (idx >= K * N) return;
  int n = idx / K, k = idx - n * K;
  WT[idx] = f2bf(W[(size_t)k * N + n]);
}

// ---------------- LayerNorm (one wave per row of 384) ----------------
template<bool SHIFT, bool INBF16>
__global__ __launch_bounds__(256) void ln_kernel(const void* __restrict__ inp,
                                                 ushort* __restrict__ outp,
                                                 const float* __restrict__ gamma,
                                                 const float* __restrict__ beta) {
  const int lane = threadIdx.x & 63;
  const int row = blockIdx.x * 4 + (threadIdx.x >> 6);
  size_t src;
  if (SHIFT) {
    int b = row / 3136, rem = row - b * 3136;
    int win = rem / 49, n = rem - win * 49;
    int wh = win >> 3, ww = win & 7;
    int i = n / 7, j = n - (n / 7) * 7;
    int h = wh * 7 + i + 3; if (h >= 56) h -= 56;
    int w = ww * 7 + j + 3; if (w >= 56) w -= 56;
    src = ((size_t)b * 3136 + h * 56 + w) * 384;
  } else {
    src = (size_t)row * 384;
  }
  float xv[6];
  float sum = 0.f, sq = 0.f;
#pragma unroll
  for (int t = 0; t < 6; t++) {
    int c = lane + t * 64;
    float f;
    if (INBF16) f = bf2f(((const ushort*)inp)[src + c]);
    else        f = ((const float*)inp)[src + c];
    xv[t] = f; sum += f; sq += f * f;
  }
#pragma unroll
  for (int o = 32; o; o >>= 1) { sum += __shfl_xor(sum, o); sq += __shfl_xor(sq, o); }
  float mean = sum * (1.f / 384.f);
  float var  = sq * (1.f / 384.f) - mean * mean;
  float inv  = rsqrtf(var + 1e-5f);
#pragma unroll
  for (int t = 0; t < 6; t++) {
    int c = lane + t * 64;
    outp[(size_t)row * 384 + c] = f2bf((xv[t] - mean) * inv * gamma[c] + beta[c]);
  }
}

// ---------------- bf16 MFMA GEMM: C[M][N] = A[M][K] * BT[N][K]^T + bias ----------------
// 128x128 block, BK=64, 2-buffer LDS, 8-slot XOR swizzle (conflict-free reads),
// vectorized epilogue via wave-private LDS scratch (16B coalesced stores).
#define EPI_QKV  0
#define EPI_PROJ 1
#define EPI_MLP1 2
#define EPI_MLP2 3

template<int EPI>
__global__ __launch_bounds__(256, 2) void gemm_kernel(
    const ushort* __restrict__ A, const ushort* __restrict__ BT,
    const float* __restrict__ bias, void* __restrict__ Cout,
    const void* __restrict__ extra, int M, int N, int K, int nbn, int cpx) {
  __shared__ ushort SH[32768];   // [buf2][A 128x64 | B 128x64] = 64 KB; reused as epi scratch
  const int tid = threadIdx.x;
  const int flat = blockIdx.x;
  const int wg = (flat & 7) * cpx + (flat >> 3);   // bijective XCD swizzle (nwg%8==0)
  const int bm = wg / nbn, bn = wg - bm * nbn;
  const int m0 = bm * 128, n0 = bn * 128;
  const int lane = tid & 63, wave = tid >> 6;
  const int wr = (wave >> 1) * 64, wc = (wave & 1) * 64;
  const int fr = lane & 15, fq = lane >> 4;
  f32x4 acc[4][4] = {};

  // staging: wave stages A rows [wave*32,+32) and B rows [wave*32,+32); 8 rows/DMA.
  // LDS slot s of row r holds global k-slot (s ^ (r&7)); source pre-swizzled.
  const int r8   = lane >> 3;                                    // 0..7
  const size_t a_base = (size_t)(m0 + wave * 32 + r8) * K + (((lane & 7) ^ r8) * 8);
  const size_t b_base = (size_t)(n0 + wave * 32 + r8) * K + (((lane & 7) ^ r8) * 8);

#define STAGE(c, kt_) do {                                        \
    const ushort* ga = A  + a_base + (kt_);                       \
    const ushort* gb = BT + b_base + (kt_);                       \
    ushort* la = SH + (c) * 8192 + wave * 2048;                   \
    ushort* lb = SH + 16384 + (c) * 8192 + wave * 2048;           \
    gload_lds16(ga,          la);                                 \
    gload_lds16(ga +  8 * K, la +  512);                          \
    gload_lds16(ga + 16 * K, la + 1024);                          \
    gload_lds16(ga + 24 * K, la + 1536);                          \
    gload_lds16(gb,          lb);                                 \
    gload_lds16(gb +  8 * K, lb +  512);                          \
    gload_lds16(gb + 16 * K, lb + 1024);                          \
    gload_lds16(gb + 24 * K, lb + 1536);                          \
  } while (0)

  const int NT = K >> 6;
  STAGE(0, 0);
  asm volatile("s_waitcnt vmcnt(0) lgkmcnt(0)" ::: "memory");
  __builtin_amdgcn_s_barrier();
  __builtin_amdgcn_sched_barrier(0);

  int cur = 0;
  for (int t = 0; t < NT; ++t) {
    if (t + 1 < NT) STAGE(cur ^ 1, (t + 1) * 64);
#pragma unroll
    for (int kk = 0; kk < 2; kk++) {
      bf16x8 a[4], b[4];
#pragma unroll
      for (int i = 0; i < 4; i++) {
        int ra = wr + i * 16 + fr;
        a[i] = *(const bf16x8*)&SH[cur * 8192 + ra * 64 + (((fq + kk * 4) ^ (ra & 7)) * 8)];
      }
#pragma unroll
      for (int j = 0; j < 4; j++) {
        int rb = wc + j * 16 + fr;
        b[j] = *(const bf16x8*)&SH[16384 + cur * 8192 + rb * 64 + (((fq + kk * 4) ^ (rb & 7)) * 8)];
      }
#pragma unroll
      for (int i = 0; i < 4; i++)
#pragma unroll
        for (int j = 0; j < 4; j++)
          acc[i][j] = __builtin_amdgcn_mfma_f32_16x16x32_bf16(a[i], b[j], acc[i][j], 0, 0, 0);
    }
    if (t + 1 < NT) {
      asm volatile("s_waitcnt vmcnt(0) lgkmcnt(0)" ::: "memory");
      __builtin_amdgcn_s_barrier();
      __builtin_amdgcn_sched_barrier(0);
      cur ^= 1;
    }
  }
#undef STAGE

  // -------- epilogue: acc -> wave-private LDS scratch -> coalesced wide stores --------
  __syncthreads();   // all waves done reading staging buffers
  float biasv[4];
#pragma unroll
  for (int j = 0; j < 4; j++) biasv[j] = bias[n0 + wc + j * 16 + fr];

  if constexpr (EPI == EPI_MLP2) {
    // fp32 out + bf16 residual; 2 chunks of 32 rows; scratch [32][66] f32 per wave
    float* scr = (float*)SH + wave * 2112;
    const float* dummy = nullptr; (void)dummy;
#pragma unroll
    for (int c = 0; c < 2; c++) {
#pragma unroll
      for (int i = 0; i < 2; i++)
#pragma unroll
        for (int j = 0; j < 4; j++)
#pragma unroll
          for (int r = 0; r < 4; r++)
            scr[(i * 16 + fq * 4 + r) * 66 + j * 16 + fr] = acc[c * 2 + i][j][r] + biasv[j];
      asm volatile("" ::: "memory");
#pragma unroll
      for (int it = 0; it < 8; it++) {
        int row = it * 4 + (lane >> 4);
        f32x4 v = *(const f32x4*)&scr[row * 66 + (lane & 15) * 4];
        int m = m0 + wr + c * 32 + row;
        int col0 = n0 + wc + (lane & 15) * 4;
        ushort4 xv = *(const ushort4*)((const ushort*)extra + (size_t)m * N + col0);
        v[0] += bf2f(xv.x); v[1] += bf2f(xv.y); v[2] += bf2f(xv.z); v[3] += bf2f(xv.w);
        *(f32x4*)((float*)Cout + (size_t)m * N + col0) = v;
      }
      asm volatile("" ::: "memory");
    }
  } else {
    // bf16 out; scratch [64][68] ushort per wave
    ushort* scr = SH + wave * 4352;
#pragma unroll
    for (int i = 0; i < 4; i++)
#pragma unroll
      for (int j = 0; j < 4; j++)
#pragma unroll
        for (int r = 0; r < 4; r++) {
          float val = acc[i][j][r] + biasv[j];
          if constexpr (EPI == EPI_MLP1) val = gelu_fast(val);
          scr[(i * 16 + fq * 4 + r) * 68 + j * 16 + fr] = f2bf(val);
        }
    asm volatile("" ::: "memory");
#pragma unroll
    for (int it = 0; it < 8; it++) {
      int row = it * 8 + (lane >> 3);
      int m = m0 + wr + row;
      int col0 = n0 + wc + (lane & 7) * 8;
      ushort v[8];
      *(bf16x8*)v = *(const bf16x8*)&scr[row * 68 + (lane & 7) * 8];
      if constexpr (EPI == EPI_PROJ) {
        int b_ = m / 3136, rem = m - b_ * 3136;
        int win = rem / 49, nn = rem - win * 49;
        int wh = win >> 3, ww = win & 7;
        int ii = nn / 7, jj = nn - (nn / 7) * 7;
        int h = wh * 7 + ii + 3; if (h >= 56) h -= 56;
        int w = ww * 7 + jj + 3; if (w >= 56) w -= 56;
        size_t rowbase = ((size_t)b_ * 3136 + h * 56 + w) * 384;
        const float* e = (const float*)extra + rowbase + col0;
        ushort o[8];
#pragma unroll
        for (int k = 0; k < 8; k++) o[k] = f2bf(bf2f(v[k]) + e[k]);
        *(bf16x8*)((ushort*)Cout + rowbase + col0) = *(bf16x8*)o;
      } else {
        *(bf16x8*)((ushort*)Cout + (size_t)m * N + col0) = *(bf16x8*)v;
      }
    }
  }
}

// ---------------- windowed attention: streaming softmax, 2 waves/block ----------------
__global__ __launch_bounds__(128) void attn_kernel(
    const ushort* __restrict__ qkv, const float* __restrict__ bias_table,
    ushort* __restrict__ outp) {
  __shared__ float ksv[2][49 * 64];   // per wave: row m -> [K 0..31 | V 32..63]
  __shared__ float btab[2][169];
  __shared__ char  rgn[2][52];
  const int wave = threadIdx.x >> 6, lane = threadIdx.x & 63;
  const int gw = blockIdx.x * 2 + wave;        // 0..24575
  const int bw = gw / 12, head = gw - bw * 12;
  const ushort* base = qkv + (size_t)bw * 49 * 1152 + head * 32;

  for (int t = lane; t < 784; t += 64) {
    int row = t >> 4;
    int c0  = (t & 15) * 4;
    int src_c = (c0 < 32) ? (384 + c0) : (736 + c0);
    ushort4 u = *(const ushort4*)(base + (size_t)row * 1152 + src_c);
    float4 f = make_float4(bf2f(u.x), bf2f(u.y), bf2f(u.z), bf2f(u.w));
    *(float4*)&ksv[wave][row * 64 + c0] = f;
  }
  for (int t = lane; t < 169; t += 64) btab[wave][t] = bias_table[t * 12 + head];
  {
    int win = bw & 63, wh = win >> 3, ww = win & 7;
    if (lane < 49) {
      int i = lane / 7, j = lane - (lane / 7) * 7;
      int hs = wh * 7 + i, wsf = ww * 7 + j;
      int bh = (hs < 49) ? 0 : (hs < 53 ? 1 : 2);
      int bv = (wsf < 49) ? 0 : (wsf < 53 ? 1 : 2);
      rgn[wave][lane] = (char)(bh * 3 + bv);
    }
  }
  __syncthreads();

  const int n = (lane < 49) ? lane : 48;
  float4 q4[8];
  {
    const ushort* qp = base + (size_t)n * 1152;
#pragma unroll
    for (int t = 0; t < 8; t++) {
      ushort4 u = *(const ushort4*)(qp + t * 4);
      q4[t] = make_float4(bf2f(u.x) * 0.17677669529663689f, bf2f(u.y) * 0.17677669529663689f,
                          bf2f(u.z) * 0.17677669529663689f, bf2f(u.w) * 0.17677669529663689f);
    }
  }
  const int rn = rgn[wave][n];
  const int i_n = n / 7, j_n = n - (n / 7) * 7;
  const float* bt = &btab[wave][(i_n + 6) * 13 + (j_n + 6)];
  const float* kb = &ksv[wave][0];

  float4 o4[8] = {};
  float sum = 0.f;
  for (int im = 0; im < 7; im++) {
#pragma unroll
    for (int jm = 0; jm < 7; jm++) {
      const int m_ = im * 7 + jm;
      const float4* kk = (const float4*)(kb + m_ * 64);
      float4 d = {};
#pragma unroll
      for (int t = 0; t < 8; t++) {
        float4 kv = kk[t];
        d.x += q4[t].x * kv.x; d.y += q4[t].y * kv.y;
        d.z += q4[t].z * kv.z; d.w += q4[t].w * kv.w;
      }
      float s = (d.x + d.y) + (d.z + d.w) + bt[-im * 13 - jm]
              + ((rn == rgn[wave][m_]) ? 0.f : -100.f);
      float e = __expf(s);
      sum += e;
      const float4* vv = (const float4*)(kb + m_ * 64 + 32);
#pragma unroll
      for (int t = 0; t < 8; t++) {
        float4 w = vv[t];
        o4[t].x += e * w.x; o4[t].y += e * w.y;
        o4[t].z += e * w.z; o4[t].w += e * w.w;
      }
    }
  }
  if (lane < 49) {
    float inv = __builtin_amdgcn_rcpf(sum);
    ushort* op = outp + (size_t)(bw * 49 + n) * 384 + head * 32;
#pragma unroll
    for (int t = 0; t < 8; t++) {
      ushort4 u;
      u.x = f2bf(o4[t].x * inv); u.y = f2bf(o4[t].y * inv);
      u.z = f2bf(o4[t].z * inv); u.w = f2bf(o4[t].w * inv);
      *(ushort4*)(op + t * 4) = u;
    }
  }
}

extern "C" void kernel_launch(void* const* d_in, const int* in_sizes, int n_in,
                              void* d_out, int out_size, void* d_ws, size_t ws_size,
                              hipStream_t stream) {
  (void)in_sizes; (void)n_in; (void)out_size; (void)ws_size;
  const float* x      = (const float*)d_in[0];
  const float* W_qkv  = (const float*)d_in[1];
  const float* b_qkv  = (const float*)d_in[2];
  const float* W_proj = (const float*)d_in[3];
  const float* b_proj = (const float*)d_in[4];
  const float* btab   = (const float*)d_in[5];
  const float* gamma1 = (const float*)d_in[6];
  const float* beta1  = (const float*)d_in[7];
  const float* gamma2 = (const float*)d_in[8];
  const float* beta2  = (const float*)d_in[9];
  const float* W_mlp1 = (const float*)d_in[10];
  const float* b_mlp1 = (const float*)d_in[11];
  const float* W_mlp2 = (const float*)d_in[12];
  const float* b_mlp2 = (const float*)d_in[13];

  const int M = 100352;  // 32 * 3136 token rows

  char* ws = (char*)d_ws;
  ushort* WqkvT  = (ushort*)ws; ws += (size_t)1152 * 384 * 2;
  ushort* WprojT = (ushort*)ws; ws += (size_t)384 * 384 * 2;
  ushort* Wm1T   = (ushort*)ws; ws += (size_t)1536 * 384 * 2;
  ushort* Wm2T   = (ushort*)ws; ws += (size_t)384 * 1536 * 2;
  ushort* x1     = (ushort*)ws; ws += (size_t)M * 384 * 2;   // bf16 residual trunk
  ushort* h2     = (ushort*)ws; ws += (size_t)M * 384 * 2;
  ushort* bufB   = (ushort*)ws;                               // overlay region
  ushort* xw     = bufB;                                      // [M][384]
  ushort* qkv    = bufB + (size_t)M * 384;                    // [M][1152]
  ushort* attn_o = bufB;                                      // [M][384]  (over xw)
  ushort* g      = bufB;                                      // [M][1536] (over all)

  wtrans_kernel<<<(384 * 1152 + 255) / 256, 256, 0, stream>>>(W_qkv,  WqkvT,  384, 1152);
  wtrans_kernel<<<(384 * 384  + 255) / 256, 256, 0, stream>>>(W_proj, WprojT, 384, 384);
  wtrans_kernel<<<(384 * 1536 + 255) / 256, 256, 0, stream>>>(W_mlp1, Wm1T,   384, 1536);
  wtrans_kernel<<<(1536 * 384 + 255) / 256, 256, 0, stream>>>(W_mlp2, Wm2T,   1536, 384);

  ln_kernel<true,  false><<<M / 4, 256, 0, stream>>>(x, xw, gamma1, beta1);

  {
    int nbn = 1152 / 128, nwg = (M / 128) * nbn;
    gemm_kernel<EPI_QKV ><<<nwg, 256, 0, stream>>>(xw, WqkvT, b_qkv, qkv, nullptr, M, 1152, 384, nbn, nwg / 8);
  }
  attn_kernel<<<12288, 128, 0, stream>>>(qkv, btab, attn_o);
  {
    int nbn = 384 / 128, nwg = (M / 128) * nbn;
    gemm_kernel<EPI_PROJ><<<nwg, 256, 0, stream>>>(attn_o, WprojT, b_proj, x1, x, M, 384, 384, nbn, nwg / 8);
  }
  ln_kernel<false, true><<<M / 4, 256, 0, stream>>>(x1, h2, gamma2, beta2);
  {
    int nbn = 1536 / 128, nwg = (M / 128) * nbn;
    gemm_kernel<EPI_MLP1><<<nwg, 256, 0, stream>>>(h2, Wm1T, b_mlp1, g, nullptr, M, 1536, 384, nbn, nwg / 8);
  }
  {
    int nbn = 384 / 128, nwg = (M / 128) * nbn;
    gemm_kernel<EPI_MLP2><<<nwg, 256, 0, stream>>>(g, Wm2T, b_mlp2, d_out, x1, M, 384, 1536, nbn, nwg / 8);
  }
}

// Round 8
// 918.423 us; speedup vs baseline: 1.1909x; 1.0713x over previous
//
#include <hip/hip_runtime.h>
#include <math.h>

typedef __bf16 bf16x8 __attribute__((ext_vector_type(8)));
typedef float  f32x4  __attribute__((ext_vector_type(4)));
typedef _Float16 f16x2 __attribute__((ext_vector_type(2)));

__device__ __forceinline__ ushort f2bf(float f) {
  union { float f; unsigned u; } v; v.f = f;
  unsigned r = v.u + 0x7FFFu + ((v.u >> 16) & 1u);
  return (ushort)(r >> 16);
}
__device__ __forceinline__ float bf2f(ushort s) {
  union { unsigned u; float f; } v; v.u = ((unsigned)s) << 16;
  return v.f;
}
__device__ __forceinline__ unsigned pkrtz(float a, float b) {
  return __builtin_bit_cast(unsigned, __builtin_amdgcn_cvt_pkrtz(a, b));
}
__device__ __forceinline__ float fdot2(unsigned a, unsigned b, float c) {
  return __builtin_amdgcn_fdot2(__builtin_bit_cast(f16x2, a),
                                __builtin_bit_cast(f16x2, b), c, false);
}

__device__ __forceinline__ void gload_lds16(const ushort* g, ushort* l) {
  __builtin_amdgcn_global_load_lds((const __attribute__((address_space(1))) void*)g,
                                   (__attribute__((address_space(3))) void*)l, 16, 0, 0);
}

// fast GELU: h * sigmoid(1.5957691*h*(1+0.044715*h^2)), sigmoid via v_rcp
__device__ __forceinline__ float gelu_fast(float h) {
  float y = 1.5957691216057308f * h * (1.f + 0.044715f * h * h);
  return h * __builtin_amdgcn_rcpf(1.f + __expf(-y));
}

// ---------------- weight transpose + bf16 convert: W[K][N] -> WT[N][K] ----------------
__global__ void wtrans_kernel(const float* __restrict__ W, ushort* __restrict__ WT,
                              int K, int N) {
  int idx = blockIdx.x * 256 + threadIdx.x;
  if (idx >= K * N) return;
  int n = idx / K, k = idx - n * K;
  WT[idx] = f2bf(W[(size_t)k * N + n]);
}

// ---------------- LayerNorm (one wave per row of 384) ----------------
template<bool SHIFT, bool INBF16>
__global__ __launch_bounds__(256) void ln_kernel(const void* __restrict__ inp,
                                                 ushort* __restrict__ outp,
                                                 const float* __restrict__ gamma,
                                                 const float* __restrict__ beta) {
  const int lane = threadIdx.x & 63;
  const int row = blockIdx.x * 4 + (threadIdx.x >> 6);
  size_t src;
  if (SHIFT) {
    int b = row / 3136, rem = row - b * 3136;
    int win = rem / 49, n = rem - win * 49;
    int wh = win >> 3, ww = win & 7;
    int i = n / 7, j = n - (n / 7) * 7;
    int h = wh * 7 + i + 3; if (h >= 56) h -= 56;
    int w = ww * 7 + j + 3; if (w >= 56) w -= 56;
    src = ((size_t)b * 3136 + h * 56 + w) * 384;
  } else {
    src = (size_t)row * 384;
  }
  float xv[6];
  float sum = 0.f, sq = 0.f;
#pragma unroll
  for (int t = 0; t < 6; t++) {
    int c = lane + t * 64;
    float f;
    if (INBF16) f = bf2f(((const ushort*)inp)[src + c]);
    else        f = ((const float*)inp)[src + c];
    xv[t] = f; sum += f; sq += f * f;
  }
#pragma unroll
  for (int o = 32; o; o >>= 1) { sum += __shfl_xor(sum, o); sq += __shfl_xor(sq, o); }
  float mean = sum * (1.f / 384.f);
  float var  = sq * (1.f / 384.f) - mean * mean;
  float inv  = rsqrtf(var + 1e-5f);
#pragma unroll
  for (int t = 0; t < 6; t++) {
    int c = lane + t * 64;
    outp[(size_t)row * 384 + c] = f2bf((xv[t] - mean) * inv * gamma[c] + beta[c]);
  }
}

// ---------------- bf16 MFMA GEMM: C[M][N] = A[M][K] * BT[N][K]^T + bias ----------------
// 128x128 block, BK=64, 2-buffer LDS, 8-slot XOR swizzle (conflict-free reads),
// vectorized epilogue via wave-private LDS scratch (16B coalesced stores).
#define EPI_QKV  0
#define EPI_PROJ 1
#define EPI_MLP1 2
#define EPI_MLP2 3

template<int EPI>
__global__ __launch_bounds__(256, 2) void gemm_kernel(
    const ushort* __restrict__ A, const ushort* __restrict__ BT,
    const float* __restrict__ bias, void* __restrict__ Cout,
    const void* __restrict__ extra, int M, int N, int K, int nbn, int cpx) {
  __shared__ ushort SH[32768];   // [buf2][A 128x64 | B 128x64] = 64 KB; reused as epi scratch
  const int tid = threadIdx.x;
  const int flat = blockIdx.x;
  const int wg = (flat & 7) * cpx + (flat >> 3);   // bijective XCD swizzle (nwg%8==0)
  const int bm = wg / nbn, bn = wg - bm * nbn;
  const int m0 = bm * 128, n0 = bn * 128;
  const int lane = tid & 63, wave = tid >> 6;
  const int wr = (wave >> 1) * 64, wc = (wave & 1) * 64;
  const int fr = lane & 15, fq = lane >> 4;
  f32x4 acc[4][4] = {};

  // staging: wave stages A rows [wave*32,+32) and B rows [wave*32,+32); 8 rows/DMA.
  // LDS slot s of row r holds global k-slot (s ^ (r&7)); source pre-swizzled.
  const int r8   = lane >> 3;                                    // 0..7
  const size_t a_base = (size_t)(m0 + wave * 32 + r8) * K + (((lane & 7) ^ r8) * 8);
  const size_t b_base = (size_t)(n0 + wave * 32 + r8) * K + (((lane & 7) ^ r8) * 8);

#define STAGE(c, kt_) do {                                        \
    const ushort* ga = A  + a_base + (kt_);                       \
    const ushort* gb = BT + b_base + (kt_);                       \
    ushort* la = SH + (c) * 8192 + wave * 2048;                   \
    ushort* lb = SH + 16384 + (c) * 8192 + wave * 2048;           \
    gload_lds16(ga,          la);                                 \
    gload_lds16(ga +  8 * K, la +  512);                          \
    gload_lds16(ga + 16 * K, la + 1024);                          \
    gload_lds16(ga + 24 * K, la + 1536);                          \
    gload_lds16(gb,          lb);                                 \
    gload_lds16(gb +  8 * K, lb +  512);                          \
    gload_lds16(gb + 16 * K, lb + 1024);                          \
    gload_lds16(gb + 24 * K, lb + 1536);                          \
  } while (0)

  const int NT = K >> 6;
  STAGE(0, 0);
  asm volatile("s_waitcnt vmcnt(0) lgkmcnt(0)" ::: "memory");
  __builtin_amdgcn_s_barrier();
  __builtin_amdgcn_sched_barrier(0);

  int cur = 0;
  for (int t = 0; t < NT; ++t) {
    if (t + 1 < NT) STAGE(cur ^ 1, (t + 1) * 64);
#pragma unroll
    for (int kk = 0; kk < 2; kk++) {
      bf16x8 a[4], b[4];
#pragma unroll
      for (int i = 0; i < 4; i++) {
        int ra = wr + i * 16 + fr;
        a[i] = *(const bf16x8*)&SH[cur * 8192 + ra * 64 + (((fq + kk * 4) ^ (ra & 7)) * 8)];
      }
#pragma unroll
      for (int j = 0; j < 4; j++) {
        int rb = wc + j * 16 + fr;
        b[j] = *(const bf16x8*)&SH[16384 + cur * 8192 + rb * 64 + (((fq + kk * 4) ^ (rb & 7)) * 8)];
      }
#pragma unroll
      for (int i = 0; i < 4; i++)
#pragma unroll
        for (int j = 0; j < 4; j++)
          acc[i][j] = __builtin_amdgcn_mfma_f32_16x16x32_bf16(a[i], b[j], acc[i][j], 0, 0, 0);
    }
    if (t + 1 < NT) {
      asm volatile("s_waitcnt vmcnt(0) lgkmcnt(0)" ::: "memory");
      __builtin_amdgcn_s_barrier();
      __builtin_amdgcn_sched_barrier(0);
      cur ^= 1;
    }
  }
#undef STAGE

  // -------- epilogue: acc -> wave-private LDS scratch -> coalesced wide stores --------
  __syncthreads();   // all waves done reading staging buffers
  float biasv[4];
#pragma unroll
  for (int j = 0; j < 4; j++) biasv[j] = bias[n0 + wc + j * 16 + fr];

  if constexpr (EPI == EPI_MLP2) {
    // fp32 out + bf16 residual; 2 chunks of 32 rows; scratch [32][66] f32 per wave
    float* scr = (float*)SH + wave * 2112;
#pragma unroll
    for (int c = 0; c < 2; c++) {
#pragma unroll
      for (int i = 0; i < 2; i++)
#pragma unroll
        for (int j = 0; j < 4; j++)
#pragma unroll
          for (int r = 0; r < 4; r++)
            scr[(i * 16 + fq * 4 + r) * 66 + j * 16 + fr] = acc[c * 2 + i][j][r] + biasv[j];
      asm volatile("" ::: "memory");
#pragma unroll
      for (int it = 0; it < 8; it++) {
        int row = it * 4 + (lane >> 4);
        f32x4 v = *(const f32x4*)&scr[row * 66 + (lane & 15) * 4];
        int m = m0 + wr + c * 32 + row;
        int col0 = n0 + wc + (lane & 15) * 4;
        ushort4 xv = *(const ushort4*)((const ushort*)extra + (size_t)m * N + col0);
        v[0] += bf2f(xv.x); v[1] += bf2f(xv.y); v[2] += bf2f(xv.z); v[3] += bf2f(xv.w);
        *(f32x4*)((float*)Cout + (size_t)m * N + col0) = v;
      }
      asm volatile("" ::: "memory");
    }
  } else {
    // bf16 out; scratch [64][68] ushort per wave
    ushort* scr = SH + wave * 4352;
#pragma unroll
    for (int i = 0; i < 4; i++)
#pragma unroll
      for (int j = 0; j < 4; j++)
#pragma unroll
        for (int r = 0; r < 4; r++) {
          float val = acc[i][j][r] + biasv[j];
          if constexpr (EPI == EPI_MLP1) val = gelu_fast(val);
          scr[(i * 16 + fq * 4 + r) * 68 + j * 16 + fr] = f2bf(val);
        }
    asm volatile("" ::: "memory");
#pragma unroll
    for (int it = 0; it < 8; it++) {
      int row = it * 8 + (lane >> 3);
      int m = m0 + wr + row;
      int col0 = n0 + wc + (lane & 7) * 8;
      ushort v[8];
      *(bf16x8*)v = *(const bf16x8*)&scr[row * 68 + (lane & 7) * 8];
      if constexpr (EPI == EPI_PROJ) {
        int b_ = m / 3136, rem = m - b_ * 3136;
        int win = rem / 49, nn = rem - win * 49;
        int wh = win >> 3, ww = win & 7;
        int ii = nn / 7, jj = nn - (nn / 7) * 7;
        int h = wh * 7 + ii + 3; if (h >= 56) h -= 56;
        int w = ww * 7 + jj + 3; if (w >= 56) w -= 56;
        size_t rowbase = ((size_t)b_ * 3136 + h * 56 + w) * 384;
        const float* e = (const float*)extra + rowbase + col0;
        ushort o[8];
#pragma unroll
        for (int k = 0; k < 8; k++) o[k] = f2bf(bf2f(v[k]) + e[k]);
        *(bf16x8*)((ushort*)Cout + rowbase + col0) = *(bf16x8*)o;
      } else {
        *(bf16x8*)((ushort*)Cout + (size_t)m * N + col0) = *(bf16x8*)v;
      }
    }
  }
}

// ---------------- windowed attention: streaming softmax, f16 dot2 math ----------------
// K in LDS as f16 pairs over d: k_lds[m][i] = (k[m][2i], k[m][2i+1])
// V in LDS as f16 pairs over m: v_lds[d][j] = (v[2j][d], v[2j+1][d]), padded to 28 pairs
__global__ __launch_bounds__(128) void attn_kernel(
    const ushort* __restrict__ qkv, const float* __restrict__ bias_table,
    ushort* __restrict__ outp) {
  __shared__ unsigned k_lds[2][49][16];
  __shared__ unsigned v_lds[2][32][28];
  __shared__ float btab[2][169];
  __shared__ char  rgn[2][52];
  const int wave = threadIdx.x >> 6, lane = threadIdx.x & 63;
  const int gw = blockIdx.x * 2 + wave;        // 0..24575
  const int bw = gw / 12, head = gw - bw * 12;
  const ushort* base = qkv + (size_t)bw * 49 * 1152 + head * 32;

  // stage K: 392 items = (m, 4-col chunk)
  for (int t = lane; t < 392; t += 64) {
    int m = t >> 3, c4 = t & 7;
    ushort4 u = *(const ushort4*)(base + (size_t)m * 1152 + 384 + c4 * 4);
    *(uint2*)&k_lds[wave][m][c4 * 2] =
        make_uint2(pkrtz(bf2f(u.x), bf2f(u.y)), pkrtz(bf2f(u.z), bf2f(u.w)));
  }
  // stage V: 224 items = (m-pair, 4-col chunk); rows >48 are zero
  for (int t = lane; t < 224; t += 64) {
    int m2 = t >> 3, c4 = t & 7;
    float4 f0 = make_float4(0.f, 0.f, 0.f, 0.f), f1 = f0;
    if (m2 <= 24) {
      ushort4 u = *(const ushort4*)(base + (size_t)(2 * m2) * 1152 + 768 + c4 * 4);
      f0 = make_float4(bf2f(u.x), bf2f(u.y), bf2f(u.z), bf2f(u.w));
    }
    if (m2 <= 23) {
      ushort4 u = *(const ushort4*)(base + (size_t)(2 * m2 + 1) * 1152 + 768 + c4 * 4);
      f1 = make_float4(bf2f(u.x), bf2f(u.y), bf2f(u.z), bf2f(u.w));
    }
    v_lds[wave][c4 * 4 + 0][m2] = pkrtz(f0.x, f1.x);
    v_lds[wave][c4 * 4 + 1][m2] = pkrtz(f0.y, f1.y);
    v_lds[wave][c4 * 4 + 2][m2] = pkrtz(f0.z, f1.z);
    v_lds[wave][c4 * 4 + 3][m2] = pkrtz(f0.w, f1.w);
  }
  for (int t = lane; t < 169; t += 64) btab[wave][t] = bias_table[t * 12 + head];
  {
    int win = bw & 63, wh = win >> 3, ww = win & 7;
    if (lane < 49) {
      int i = lane / 7, j = lane - (lane / 7) * 7;
      int hs = wh * 7 + i, wsf = ww * 7 + j;
      int bh = (hs < 49) ? 0 : (hs < 53 ? 1 : 2);
      int bv = (wsf < 49) ? 0 : (wsf < 53 ? 1 : 2);
      rgn[wave][lane] = (char)(bh * 3 + bv);
    }
  }
  __syncthreads();

  const int n = (lane < 49) ? lane : 48;
  unsigned q2[16];
  {
    const ushort* qp = base + (size_t)n * 1152;
#pragma unroll
    for (int t = 0; t < 8; t++) {
      ushort4 u = *(const ushort4*)(qp + t * 4);
      const float sc = 0.17677669529663689f;
      q2[2 * t]     = pkrtz(bf2f(u.x) * sc, bf2f(u.y) * sc);
      q2[2 * t + 1] = pkrtz(bf2f(u.z) * sc, bf2f(u.w) * sc);
    }
  }
  const char rn = rgn[wave][n];
  const int i_n = n / 7, j_n = n - (n / 7) * 7;
  const float* bt = &btab[wave][(i_n + 6) * 13 + (j_n + 6)];

  auto qk_one = [&](int m) -> float {
    const uint4* kr = (const uint4*)&k_lds[wave][m][0];
    uint4 k0 = kr[0], k1 = kr[1], k2 = kr[2], k3 = kr[3];
    float a0 = 0.f, a1 = 0.f, a2 = 0.f, a3 = 0.f;
    a0 = fdot2(k0.x, q2[0],  a0); a1 = fdot2(k0.y, q2[1],  a1);
    a2 = fdot2(k0.z, q2[2],  a2); a3 = fdot2(k0.w, q2[3],  a3);
    a0 = fdot2(k1.x, q2[4],  a0); a1 = fdot2(k1.y, q2[5],  a1);
    a2 = fdot2(k1.z, q2[6],  a2); a3 = fdot2(k1.w, q2[7],  a3);
    a0 = fdot2(k2.x, q2[8],  a0); a1 = fdot2(k2.y, q2[9],  a1);
    a2 = fdot2(k2.z, q2[10], a2); a3 = fdot2(k2.w, q2[11], a3);
    a0 = fdot2(k3.x, q2[12], a0); a1 = fdot2(k3.y, q2[13], a1);
    a2 = fdot2(k3.z, q2[14], a2); a3 = fdot2(k3.w, q2[15], a3);
    int im = m / 7, jm = m - (m / 7) * 7;
    float s = (a0 + a1) + (a2 + a3) + bt[-im * 13 - jm];
    s += (rgn[wave][m] == rn) ? 0.f : -100.f;
    return __expf(s);
  };

  float sum = 0.f;
  unsigned p2[28];
#pragma unroll
  for (int m2 = 0; m2 < 25; m2++) {
    float eA = qk_one(2 * m2);
    float eB = (m2 < 24) ? qk_one(2 * m2 + 1) : 0.f;
    sum += eA + eB;
    p2[m2] = pkrtz(eA, eB);
  }
  p2[25] = 0; p2[26] = 0; p2[27] = 0;

  const float invs = __builtin_amdgcn_rcpf(sum);
  ushort* op = outp + (size_t)(bw * 49 + n) * 384 + head * 32;
#pragma unroll
  for (int dc = 0; dc < 4; dc++) {
    ushort u8[8];
#pragma unroll
    for (int j = 0; j < 8; j++) {
      const uint4* vr = (const uint4*)&v_lds[wave][dc * 8 + j][0];
      float a0 = 0.f, a1 = 0.f, a2 = 0.f, a3 = 0.f;
#pragma unroll
      for (int t7 = 0; t7 < 7; t7++) {
        uint4 vv = vr[t7];
        a0 = fdot2(vv.x, p2[t7 * 4 + 0], a0);
        a1 = fdot2(vv.y, p2[t7 * 4 + 1], a1);
        a2 = fdot2(vv.z, p2[t7 * 4 + 2], a2);
        a3 = fdot2(vv.w, p2[t7 * 4 + 3], a3);
      }
      u8[j] = f2bf(((a0 + a1) + (a2 + a3)) * invs);
    }
    if (lane < 49) *(bf16x8*)(op + dc * 8) = *(bf16x8*)u8;
  }
}

extern "C" void kernel_launch(void* const* d_in, const int* in_sizes, int n_in,
                              void* d_out, int out_size, void* d_ws, size_t ws_size,
                              hipStream_t stream) {
  (void)in_sizes; (void)n_in; (void)out_size; (void)ws_size;
  const float* x      = (const float*)d_in[0];
  const float* W_qkv  = (const float*)d_in[1];
  const float* b_qkv  = (const float*)d_in[2];
  const float* W_proj = (const float*)d_in[3];
  const float* b_proj = (const float*)d_in[4];
  const float* btab   = (const float*)d_in[5];
  const float* gamma1 = (const float*)d_in[6];
  const float* beta1  = (const float*)d_in[7];
  const float* gamma2 = (const float*)d_in[8];
  const float* beta2  = (const float*)d_in[9];
  const float* W_mlp1 = (const float*)d_in[10];
  const float* b_mlp1 = (const float*)d_in[11];
  const float* W_mlp2 = (const float*)d_in[12];
  const float* b_mlp2 = (const float*)d_in[13];

  const int M = 100352;  // 32 * 3136 token rows

  char* ws = (char*)d_ws;
  ushort* WqkvT  = (ushort*)ws; ws += (size_t)1152 * 384 * 2;
  ushort* WprojT = (ushort*)ws; ws += (size_t)384 * 384 * 2;
  ushort* Wm1T   = (ushort*)ws; ws += (size_t)1536 * 384 * 2;
  ushort* Wm2T   = (ushort*)ws; ws += (size_t)384 * 1536 * 2;
  ushort* x1     = (ushort*)ws; ws += (size_t)M * 384 * 2;   // bf16 residual trunk
  ushort* h2     = (ushort*)ws; ws += (size_t)M * 384 * 2;
  ushort* bufB   = (ushort*)ws;                               // overlay region
  ushort* xw     = bufB;                                      // [M][384]
  ushort* qkv    = bufB + (size_t)M * 384;                    // [M][1152]
  ushort* attn_o = bufB;                                      // [M][384]  (over xw)
  ushort* g      = bufB;                                      // [M][1536] (over all)

  wtrans_kernel<<<(384 * 1152 + 255) / 256, 256, 0, stream>>>(W_qkv,  WqkvT,  384, 1152);
  wtrans_kernel<<<(384 * 384  + 255) / 256, 256, 0, stream>>>(W_proj, WprojT, 384, 384);
  wtrans_kernel<<<(384 * 1536 + 255) / 256, 256, 0, stream>>>(W_mlp1, Wm1T,   384, 1536);
  wtrans_kernel<<<(1536 * 384 + 255) / 256, 256, 0, stream>>>(W_mlp2, Wm2T,   1536, 384);

  ln_kernel<true,  false><<<M / 4, 256, 0, stream>>>(x, xw, gamma1, beta1);

  {
    int nbn = 1152 / 128, nwg = (M / 128) * nbn;
    gemm_kernel<EPI_QKV ><<<nwg, 256, 0, stream>>>(xw, WqkvT, b_qkv, qkv, nullptr, M, 1152, 384, nbn, nwg / 8);
  }
  attn_kernel<<<12288, 128, 0, stream>>>(qkv, btab, attn_o);
  {
    int nbn = 384 / 128, nwg = (M / 128) * nbn;
    gemm_kernel<EPI_PROJ><<<nwg, 256, 0, stream>>>(attn_o, WprojT, b_proj, x1, x, M, 384, 384, nbn, nwg / 8);
  }
  ln_kernel<false, true><<<M / 4, 256, 0, stream>>>(x1, h2, gamma2, beta2);
  {
    int nbn = 1536 / 128, nwg = (M / 128) * nbn;
    gemm_kernel<EPI_MLP1><<<nwg, 256, 0, stream>>>(h2, Wm1T, b_mlp1, g, nullptr, M, 1536, 384, nbn, nwg / 8);
  }
  {
    int nbn = 384 / 128, nwg = (M / 128) * nbn;
    gemm_kernel<EPI_MLP2><<<nwg, 256, 0, stream>>>(g, Wm2T, b_mlp2, d_out, x1, M, 384, 1536, nbn, nwg / 8);
  }
}

// Round 9
// 904.279 us; speedup vs baseline: 1.2096x; 1.0156x over previous
//
#include <hip/hip_runtime.h>
#include <math.h>

typedef __bf16 bf16x8 __attribute__((ext_vector_type(8)));
typedef float  f32x4  __attribute__((ext_vector_type(4)));
typedef _Float16 f16x2 __attribute__((ext_vector_type(2)));

__device__ __forceinline__ ushort f2bf(float f) {
  union { float f; unsigned u; } v; v.f = f;
  unsigned r = v.u + 0x7FFFu + ((v.u >> 16) & 1u);
  return (ushort)(r >> 16);
}
__device__ __forceinline__ float bf2f(ushort s) {
  union { unsigned u; float f; } v; v.u = ((unsigned)s) << 16;
  return v.f;
}
__device__ __forceinline__ unsigned pkrtz(float a, float b) {
  return __builtin_bit_cast(unsigned, __builtin_amdgcn_cvt_pkrtz(a, b));
}
__device__ __forceinline__ float fdot2(unsigned a, unsigned b, float c) {
  return __builtin_amdgcn_fdot2(__builtin_bit_cast(f16x2, a),
                                __builtin_bit_cast(f16x2, b), c, false);
}

__device__ __forceinline__ void gload_lds16(const ushort* g, ushort* l) {
  __builtin_amdgcn_global_load_lds((const __attribute__((address_space(1))) void*)g,
                                   (__attribute__((address_space(3))) void*)l, 16, 0, 0);
}

// fast GELU: h * sigmoid(1.5957691*h*(1+0.044715*h^2)), sigmoid via v_rcp
__device__ __forceinline__ float gelu_fast(float h) {
  float y = 1.5957691216057308f * h * (1.f + 0.044715f * h * h);
  return h * __builtin_amdgcn_rcpf(1.f + __expf(-y));
}

// ---------------- weight transpose + bf16 convert: W[K][N] -> WT[N][K] ----------------
__global__ void wtrans_kernel(const float* __restrict__ W, ushort* __restrict__ WT,
                              int K, int N) {
  int idx = blockIdx.x * 256 + threadIdx.x;
  if (idx >= K * N) return;
  int n = idx / K, k = idx - n * K;
  WT[idx] = f2bf(W[(size_t)k * N + n]);
}

// ---------------- LayerNorm (one wave per row of 384) ----------------
template<bool SHIFT, bool INBF16>
__global__ __launch_bounds__(256) void ln_kernel(const void* __restrict__ inp,
                                                 ushort* __restrict__ outp,
                                                 const float* __restrict__ gamma,
                                                 const float* __restrict__ beta) {
  const int lane = threadIdx.x & 63;
  const int row = blockIdx.x * 4 + (threadIdx.x >> 6);
  size_t src;
  if (SHIFT) {
    int b = row / 3136, rem = row - b * 3136;
    int win = rem / 49, n = rem - win * 49;
    int wh = win >> 3, ww = win & 7;
    int i = n / 7, j = n - (n / 7) * 7;
    int h = wh * 7 + i + 3; if (h >= 56) h -= 56;
    int w = ww * 7 + j + 3; if (w >= 56) w -= 56;
    src = ((size_t)b * 3136 + h * 56 + w) * 384;
  } else {
    src = (size_t)row * 384;
  }
  float xv[6];
  float sum = 0.f, sq = 0.f;
#pragma unroll
  for (int t = 0; t < 6; t++) {
    int c = lane + t * 64;
    float f;
    if (INBF16) f = bf2f(((const ushort*)inp)[src + c]);
    else        f = ((const float*)inp)[src + c];
    xv[t] = f; sum += f; sq += f * f;
  }
#pragma unroll
  for (int o = 32; o; o >>= 1) { sum += __shfl_xor(sum, o); sq += __shfl_xor(sq, o); }
  float mean = sum * (1.f / 384.f);
  float var  = sq * (1.f / 384.f) - mean * mean;
  float inv  = rsqrtf(var + 1e-5f);
#pragma unroll
  for (int t = 0; t < 6; t++) {
    int c = lane + t * 64;
    outp[(size_t)row * 384 + c] = f2bf((xv[t] - mean) * inv * gamma[c] + beta[c]);
  }
}

// ---------------- bf16 MFMA GEMM: C[M][N] = A[M][K] * BT[N][K]^T + bias ----------------
// 128x128 block, 8 waves (64x32 per wave), BK=64, 2-buffer LDS, 8-slot XOR swizzle,
// vectorized epilogue via per-wave LDS scratch. 16 waves/CU (4/SIMD) for TLP.
#define EPI_QKV  0
#define EPI_PROJ 1
#define EPI_MLP1 2
#define EPI_MLP2 3

template<int EPI>
__global__ __launch_bounds__(512, 4) void gemm_kernel(
    const ushort* __restrict__ A, const ushort* __restrict__ BT,
    const float* __restrict__ bias, void* __restrict__ Cout,
    const void* __restrict__ extra, int M, int N, int K, int nbn, int cpx) {
  __shared__ ushort SH[32768];   // [A 2x(128x64) | B 2x(128x64)] = 64 KB; epi scratch reuse
  const int tid = threadIdx.x;
  const int flat = blockIdx.x;
  const int wg = (flat & 7) * cpx + (flat >> 3);   // bijective XCD swizzle (nwg%8==0)
  const int bm = wg / nbn, bn = wg - bm * nbn;
  const int m0 = bm * 128, n0 = bn * 128;
  const int lane = tid & 63, wave = tid >> 6;      // 8 waves
  const int wr = (wave >> 2) * 64, wc = (wave & 3) * 32;
  const int fr = lane & 15, fq = lane >> 4;
  f32x4 acc[4][2] = {};

  // staging: wave stages A rows [wave*16,+16) and B rows [wave*16,+16); 8 rows/DMA.
  // LDS slot s of row r holds global k-slot (s ^ (r&7)); source pre-swizzled.
  const int r8 = lane >> 3;                        // 0..7
  const size_t a_base = (size_t)(m0 + wave * 16 + r8) * K + (((lane & 7) ^ r8) * 8);
  const size_t b_base = (size_t)(n0 + wave * 16 + r8) * K + (((lane & 7) ^ r8) * 8);

#define STAGE(c, kt_) do {                                        \
    const ushort* ga = A  + a_base + (kt_);                       \
    const ushort* gb = BT + b_base + (kt_);                       \
    ushort* la = SH + (c) * 8192 + wave * 1024;                   \
    ushort* lb = SH + 16384 + (c) * 8192 + wave * 1024;           \
    gload_lds16(ga,         la);                                  \
    gload_lds16(ga + 8 * K, la + 512);                            \
    gload_lds16(gb,         lb);                                  \
    gload_lds16(gb + 8 * K, lb + 512);                            \
  } while (0)

  const int NT = K >> 6;
  STAGE(0, 0);
  asm volatile("s_waitcnt vmcnt(0) lgkmcnt(0)" ::: "memory");
  __builtin_amdgcn_s_barrier();
  __builtin_amdgcn_sched_barrier(0);

  int cur = 0;
  for (int t = 0; t < NT; ++t) {
    if (t + 1 < NT) STAGE(cur ^ 1, (t + 1) * 64);
#pragma unroll
    for (int kk = 0; kk < 2; kk++) {
      bf16x8 a[4], b[2];
#pragma unroll
      for (int i = 0; i < 4; i++) {
        int ra = wr + i * 16 + fr;
        a[i] = *(const bf16x8*)&SH[cur * 8192 + ra * 64 + (((fq + kk * 4) ^ (ra & 7)) * 8)];
      }
#pragma unroll
      for (int j = 0; j < 2; j++) {
        int rb = wc + j * 16 + fr;
        b[j] = *(const bf16x8*)&SH[16384 + cur * 8192 + rb * 64 + (((fq + kk * 4) ^ (rb & 7)) * 8)];
      }
#pragma unroll
      for (int i = 0; i < 4; i++)
#pragma unroll
        for (int j = 0; j < 2; j++)
          acc[i][j] = __builtin_amdgcn_mfma_f32_16x16x32_bf16(a[i], b[j], acc[i][j], 0, 0, 0);
    }
    if (t + 1 < NT) {
      asm volatile("s_waitcnt vmcnt(0) lgkmcnt(0)" ::: "memory");
      __builtin_amdgcn_s_barrier();
      __builtin_amdgcn_sched_barrier(0);
      cur ^= 1;
    }
  }
#undef STAGE

  // -------- epilogue: acc -> per-wave LDS scratch -> coalesced wide stores --------
  __syncthreads();   // all waves done reading staging buffers
  float biasv[2];
#pragma unroll
  for (int j = 0; j < 2; j++) biasv[j] = bias[n0 + wc + j * 16 + fr];

  if constexpr (EPI == EPI_MLP2) {
    // fp32 out + bf16 residual; 2 chunks of 32 rows; scratch [32][36] f32 per wave
    float* scr = (float*)SH + wave * 1152;
#pragma unroll
    for (int c = 0; c < 2; c++) {
#pragma unroll
      for (int i = 0; i < 2; i++)
#pragma unroll
        for (int j = 0; j < 2; j++)
#pragma unroll
          for (int r = 0; r < 4; r++)
            scr[(i * 16 + fq * 4 + r) * 36 + j * 16 + fr] = acc[c * 2 + i][j][r] + biasv[j];
      asm volatile("" ::: "memory");
#pragma unroll
      for (int it = 0; it < 4; it++) {
        int row = it * 8 + (lane >> 3);
        f32x4 v = *(const f32x4*)&scr[row * 36 + (lane & 7) * 4];
        int m = m0 + wr + c * 32 + row;
        int col0 = n0 + wc + (lane & 7) * 4;
        ushort4 xv = *(const ushort4*)((const ushort*)extra + (size_t)m * N + col0);
        v[0] += bf2f(xv.x); v[1] += bf2f(xv.y); v[2] += bf2f(xv.z); v[3] += bf2f(xv.w);
        *(f32x4*)((float*)Cout + (size_t)m * N + col0) = v;
      }
      asm volatile("" ::: "memory");
    }
  } else {
    // bf16 out; scratch [64][36] ushort per wave
    ushort* scr = SH + wave * 2304;
#pragma unroll
    for (int i = 0; i < 4; i++)
#pragma unroll
      for (int j = 0; j < 2; j++)
#pragma unroll
        for (int r = 0; r < 4; r++) {
          float val = acc[i][j][r] + biasv[j];
          if constexpr (EPI == EPI_MLP1) val = gelu_fast(val);
          scr[(i * 16 + fq * 4 + r) * 36 + j * 16 + fr] = f2bf(val);
        }
    asm volatile("" ::: "memory");
#pragma unroll
    for (int it = 0; it < 4; it++) {
      int row = it * 16 + (lane >> 2);
      int m = m0 + wr + row;
      int col0 = n0 + wc + (lane & 3) * 8;
      ushort v[8];
      *(bf16x8*)v = *(const bf16x8*)&scr[row * 36 + (lane & 3) * 8];
      if constexpr (EPI == EPI_PROJ) {
        int b_ = m / 3136, rem = m - b_ * 3136;
        int win = rem / 49, nn = rem - win * 49;
        int wh = win >> 3, ww = win & 7;
        int ii = nn / 7, jj = nn - (nn / 7) * 7;
        int h = wh * 7 + ii + 3; if (h >= 56) h -= 56;
        int w = ww * 7 + jj + 3; if (w >= 56) w -= 56;
        size_t rowbase = ((size_t)b_ * 3136 + h * 56 + w) * 384;
        const float* e = (const float*)extra + rowbase + col0;
        ushort o[8];
#pragma unroll
        for (int k = 0; k < 8; k++) o[k] = f2bf(bf2f(v[k]) + e[k]);
        *(bf16x8*)((ushort*)Cout + rowbase + col0) = *(bf16x8*)o;
      } else {
        *(bf16x8*)((ushort*)Cout + (size_t)m * N + col0) = *(bf16x8*)v;
      }
    }
  }
}

// ---------------- windowed attention: streaming softmax, f16 dot2 math ----------------
__global__ __launch_bounds__(128) void attn_kernel(
    const ushort* __restrict__ qkv, const float* __restrict__ bias_table,
    ushort* __restrict__ outp) {
  __shared__ unsigned k_lds[2][49][16];
  __shared__ unsigned v_lds[2][32][28];
  __shared__ float btab[2][169];
  __shared__ char  rgn[2][52];
  const int wave = threadIdx.x >> 6, lane = threadIdx.x & 63;
  const int gw = blockIdx.x * 2 + wave;        // 0..24575
  const int bw = gw / 12, head = gw - bw * 12;
  const ushort* base = qkv + (size_t)bw * 49 * 1152 + head * 32;

  for (int t = lane; t < 392; t += 64) {
    int m = t >> 3, c4 = t & 7;
    ushort4 u = *(const ushort4*)(base + (size_t)m * 1152 + 384 + c4 * 4);
    *(uint2*)&k_lds[wave][m][c4 * 2] =
        make_uint2(pkrtz(bf2f(u.x), bf2f(u.y)), pkrtz(bf2f(u.z), bf2f(u.w)));
  }
  for (int t = lane; t < 224; t += 64) {
    int m2 = t >> 3, c4 = t & 7;
    float4 f0 = make_float4(0.f, 0.f, 0.f, 0.f), f1 = f0;
    if (m2 <= 24) {
      ushort4 u = *(const ushort4*)(base + (size_t)(2 * m2) * 1152 + 768 + c4 * 4);
      f0 = make_float4(bf2f(u.x), bf2f(u.y), bf2f(u.z), bf2f(u.w));
    }
    if (m2 <= 23) {
      ushort4 u = *(const ushort4*)(base + (size_t)(2 * m2 + 1) * 1152 + 768 + c4 * 4);
      f1 = make_float4(bf2f(u.x), bf2f(u.y), bf2f(u.z), bf2f(u.w));
    }
    v_lds[wave][c4 * 4 + 0][m2] = pkrtz(f0.x, f1.x);
    v_lds[wave][c4 * 4 + 1][m2] = pkrtz(f0.y, f1.y);
    v_lds[wave][c4 * 4 + 2][m2] = pkrtz(f0.z, f1.z);
    v_lds[wave][c4 * 4 + 3][m2] = pkrtz(f0.w, f1.w);
  }
  for (int t = lane; t < 169; t += 64) btab[wave][t] = bias_table[t * 12 + head];
  {
    int win = bw & 63, wh = win >> 3, ww = win & 7;
    if (lane < 49) {
      int i = lane / 7, j = lane - (lane / 7) * 7;
      int hs = wh * 7 + i, wsf = ww * 7 + j;
      int bh = (hs < 49) ? 0 : (hs < 53 ? 1 : 2);
      int bv = (wsf < 49) ? 0 : (wsf < 53 ? 1 : 2);
      rgn[wave][lane] = (char)(bh * 3 + bv);
    }
  }
  __syncthreads();

  const int n = (lane < 49) ? lane : 48;
  unsigned q2[16];
  {
    const ushort* qp = base + (size_t)n * 1152;
#pragma unroll
    for (int t = 0; t < 8; t++) {
      ushort4 u = *(const ushort4*)(qp + t * 4);
      const float sc = 0.17677669529663689f;
      q2[2 * t]     = pkrtz(bf2f(u.x) * sc, bf2f(u.y) * sc);
      q2[2 * t + 1] = pkrtz(bf2f(u.z) * sc, bf2f(u.w) * sc);
    }
  }
  const char rn = rgn[wave][n];
  const int i_n = n / 7, j_n = n - (n / 7) * 7;
  const float* bt = &btab[wave][(i_n + 6) * 13 + (j_n + 6)];

  auto qk_one = [&](int m) -> float {
    const uint4* kr = (const uint4*)&k_lds[wave][m][0];
    uint4 k0 = kr[0], k1 = kr[1], k2 = kr[2], k3 = kr[3];
    float a0 = 0.f, a1 = 0.f, a2 = 0.f, a3 = 0.f;
    a0 = fdot2(k0.x, q2[0],  a0); a1 = fdot2(k0.y, q2[1],  a1);
    a2 = fdot2(k0.z, q2[2],  a2); a3 = fdot2(k0.w, q2[3],  a3);
    a0 = fdot2(k1.x, q2[4],  a0); a1 = fdot2(k1.y, q2[5],  a1);
    a2 = fdot2(k1.z, q2[6],  a2); a3 = fdot2(k1.w, q2[7],  a3);
    a0 = fdot2(k2.x, q2[8],  a0); a1 = fdot2(k2.y, q2[9],  a1);
    a2 = fdot2(k2.z, q2[10], a2); a3 = fdot2(k2.w, q2[11], a3);
    a0 = fdot2(k3.x, q2[12], a0); a1 = fdot2(k3.y, q2[13], a1);
    a2 = fdot2(k3.z, q2[14], a2); a3 = fdot2(k3.w, q2[15], a3);
    int im = m / 7, jm = m - (m / 7) * 7;
    float s = (a0 + a1) + (a2 + a3) + bt[-im * 13 - jm];
    s += (rgn[wave][m] == rn) ? 0.f : -100.f;
    return __expf(s);
  };

  float sum = 0.f;
  unsigned p2[28];
#pragma unroll
  for (int m2 = 0; m2 < 25; m2++) {
    float eA = qk_one(2 * m2);
    float eB = (m2 < 24) ? qk_one(2 * m2 + 1) : 0.f;
    sum += eA + eB;
    p2[m2] = pkrtz(eA, eB);
  }
  p2[25] = 0; p2[26] = 0; p2[27] = 0;

  const float invs = __builtin_amdgcn_rcpf(sum);
  ushort* op = outp + (size_t)(bw * 49 + n) * 384 + head * 32;
#pragma unroll
  for (int dc = 0; dc < 4; dc++) {
    ushort u8[8];
#pragma unroll
    for (int j = 0; j < 8; j++) {
      const uint4* vr = (const uint4*)&v_lds[wave][dc * 8 + j][0];
      float a0 = 0.f, a1 = 0.f, a2 = 0.f, a3 = 0.f;
#pragma unroll
      for (int t7 = 0; t7 < 7; t7++) {
        uint4 vv = vr[t7];
        a0 = fdot2(vv.x, p2[t7 * 4 + 0], a0);
        a1 = fdot2(vv.y, p2[t7 * 4 + 1], a1);
        a2 = fdot2(vv.z, p2[t7 * 4 + 2], a2);
        a3 = fdot2(vv.w, p2[t7 * 4 + 3], a3);
      }
      u8[j] = f2bf(((a0 + a1) + (a2 + a3)) * invs);
    }
    if (lane < 49) *(bf16x8*)(op + dc * 8) = *(bf16x8*)u8;
  }
}

extern "C" void kernel_launch(void* const* d_in, const int* in_sizes, int n_in,
                              void* d_out, int out_size, void* d_ws, size_t ws_size,
                              hipStream_t stream) {
  (void)in_sizes; (void)n_in; (void)out_size; (void)ws_size;
  const float* x      = (const float*)d_in[0];
  const float* W_qkv  = (const float*)d_in[1];
  const float* b_qkv  = (const float*)d_in[2];
  const float* W_proj = (const float*)d_in[3];
  const float* b_proj = (const float*)d_in[4];
  const float* btab   = (const float*)d_in[5];
  const float* gamma1 = (const float*)d_in[6];
  const float* beta1  = (const float*)d_in[7];
  const float* gamma2 = (const float*)d_in[8];
  const float* beta2  = (const float*)d_in[9];
  const float* W_mlp1 = (const float*)d_in[10];
  const float* b_mlp1 = (const float*)d_in[11];
  const float* W_mlp2 = (const float*)d_in[12];
  const float* b_mlp2 = (const float*)d_in[13];

  const int M = 100352;  // 32 * 3136 token rows

  char* ws = (char*)d_ws;
  ushort* WqkvT  = (ushort*)ws; ws += (size_t)1152 * 384 * 2;
  ushort* WprojT = (ushort*)ws; ws += (size_t)384 * 384 * 2;
  ushort* Wm1T   = (ushort*)ws; ws += (size_t)1536 * 384 * 2;
  ushort* Wm2T   = (ushort*)ws; ws += (size_t)384 * 1536 * 2;
  ushort* x1     = (ushort*)ws; ws += (size_t)M * 384 * 2;   // bf16 residual trunk
  ushort* h2     = (ushort*)ws; ws += (size_t)M * 384 * 2;
  ushort* bufB   = (ushort*)ws;                               // overlay region
  ushort* xw     = bufB;                                      // [M][384]
  ushort* qkv    = bufB + (size_t)M * 384;                    // [M][1152]
  ushort* attn_o = bufB;                                      // [M][384]  (over xw)
  ushort* g      = bufB;                                      // [M][1536] (over all)

  wtrans_kernel<<<(384 * 1152 + 255) / 256, 256, 0, stream>>>(W_qkv,  WqkvT,  384, 1152);
  wtrans_kernel<<<(384 * 384  + 255) / 256, 256, 0, stream>>>(W_proj, WprojT, 384, 384);
  wtrans_kernel<<<(384 * 1536 + 255) / 256, 256, 0, stream>>>(W_mlp1, Wm1T,   384, 1536);
  wtrans_kernel<<<(1536 * 384 + 255) / 256, 256, 0, stream>>>(W_mlp2, Wm2T,   1536, 384);

  ln_kernel<true,  false><<<M / 4, 256, 0, stream>>>(x, xw, gamma1, beta1);

  {
    int nbn = 1152 / 128, nwg = (M / 128) * nbn;
    gemm_kernel<EPI_QKV ><<<nwg, 512, 0, stream>>>(xw, WqkvT, b_qkv, qkv, nullptr, M, 1152, 384, nbn, nwg / 8);
  }
  attn_kernel<<<12288, 128, 0, stream>>>(qkv, btab, attn_o);
  {
    int nbn = 384 / 128, nwg = (M / 128) * nbn;
    gemm_kernel<EPI_PROJ><<<nwg, 512, 0, stream>>>(attn_o, WprojT, b_proj, x1, x, M, 384, 384, nbn, nwg / 8);
  }
  ln_kernel<false, true><<<M / 4, 256, 0, stream>>>(x1, h2, gamma2, beta2);
  {
    int nbn = 1536 / 128, nwg = (M / 128) * nbn;
    gemm_kernel<EPI_MLP1><<<nwg, 512, 0, stream>>>(h2, Wm1T, b_mlp1, g, nullptr, M, 1536, 384, nbn, nwg / 8);
  }
  {
    int nbn = 384 / 128, nwg = (M / 128) * nbn;
    gemm_kernel<EPI_MLP2><<<nwg, 512, 0, stream>>>(g, Wm2T, b_mlp2, d_out, x1, M, 384, 1536, nbn, nwg / 8);
  }
}

// Round 10
// 868.774 us; speedup vs baseline: 1.2590x; 1.0409x over previous
//
#include <hip/hip_runtime.h>
#include <math.h>

typedef __bf16 bf16x8 __attribute__((ext_vector_type(8)));
typedef float  f32x4  __attribute__((ext_vector_type(4)));
typedef _Float16 f16x2 __attribute__((ext_vector_type(2)));

__device__ __forceinline__ ushort f2bf(float f) {
  union { float f; unsigned u; } v; v.f = f;
  unsigned r = v.u + 0x7FFFu + ((v.u >> 16) & 1u);
  return (ushort)(r >> 16);
}
__device__ __forceinline__ float bf2f(ushort s) {
  union { unsigned u; float f; } v; v.u = ((unsigned)s) << 16;
  return v.f;
}
__device__ __forceinline__ unsigned pkrtz(float a, float b) {
  return __builtin_bit_cast(unsigned, __builtin_amdgcn_cvt_pkrtz(a, b));
}
__device__ __forceinline__ float fdot2(unsigned a, unsigned b, float c) {
  return __builtin_amdgcn_fdot2(__builtin_bit_cast(f16x2, a),
                                __builtin_bit_cast(f16x2, b), c, false);
}

__device__ __forceinline__ void gload_lds16(const ushort* g, ushort* l) {
  __builtin_amdgcn_global_load_lds((const __attribute__((address_space(1))) void*)g,
                                   (__attribute__((address_space(3))) void*)l, 16, 0, 0);
}

// fast GELU: h * sigmoid(1.5957691*h*(1+0.044715*h^2)), sigmoid via v_rcp
__device__ __forceinline__ float gelu_fast(float h) {
  float y = 1.5957691216057308f * h * (1.f + 0.044715f * h * h);
  return h * __builtin_amdgcn_rcpf(1.f + __expf(-y));
}

// ---------------- weight transpose + bf16 convert: W[K][N] -> WT[N][K] ----------------
__global__ void wtrans_kernel(const float* __restrict__ W, ushort* __restrict__ WT,
                              int K, int N) {
  int idx = blockIdx.x * 256 + threadIdx.x;
  if (idx >= K * N) return;
  int n = idx / K, k = idx - n * K;
  WT[idx] = f2bf(W[(size_t)k * N + n]);
}

// ---------------- LayerNorm (one wave per row of 384) ----------------
template<bool SHIFT, bool INBF16>
__global__ __launch_bounds__(256) void ln_kernel(const void* __restrict__ inp,
                                                 ushort* __restrict__ outp,
                                                 const float* __restrict__ gamma,
                                                 const float* __restrict__ beta) {
  const int lane = threadIdx.x & 63;
  const int row = blockIdx.x * 4 + (threadIdx.x >> 6);
  size_t src;
  if (SHIFT) {
    int b = row / 3136, rem = row - b * 3136;
    int win = rem / 49, n = rem - win * 49;
    int wh = win >> 3, ww = win & 7;
    int i = n / 7, j = n - (n / 7) * 7;
    int h = wh * 7 + i + 3; if (h >= 56) h -= 56;
    int w = ww * 7 + j + 3; if (w >= 56) w -= 56;
    src = ((size_t)b * 3136 + h * 56 + w) * 384;
  } else {
    src = (size_t)row * 384;
  }
  float xv[6];
  float sum = 0.f, sq = 0.f;
#pragma unroll
  for (int t = 0; t < 6; t++) {
    int c = lane + t * 64;
    float f;
    if (INBF16) f = bf2f(((const ushort*)inp)[src + c]);
    else        f = ((const float*)inp)[src + c];
    xv[t] = f; sum += f; sq += f * f;
  }
#pragma unroll
  for (int o = 32; o; o >>= 1) { sum += __shfl_xor(sum, o); sq += __shfl_xor(sq, o); }
  float mean = sum * (1.f / 384.f);
  float var  = sq * (1.f / 384.f) - mean * mean;
  float inv  = rsqrtf(var + 1e-5f);
#pragma unroll
  for (int t = 0; t < 6; t++) {
    int c = lane + t * 64;
    outp[(size_t)row * 384 + c] = f2bf((xv[t] - mean) * inv * gamma[c] + beta[c]);
  }
}

// ---------------- bf16 MFMA GEMM: C[M][N] = A[M][K] * BT[N][K]^T + bias ----------------
// 128x128 block, 8 waves (64x32/wave), BK=32, 3-buffer LDS (48KB -> 2 blocks/CU),
// 2-deep prefetch with counted vmcnt(2), raw s_barrier, XOR-swizzle key (row>>1)&3,
// vectorized epilogue via per-wave LDS scratch.
#define EPI_QKV  0
#define EPI_PROJ 1
#define EPI_MLP1 2
#define EPI_MLP2 3

template<int EPI>
__global__ __launch_bounds__(512, 4) void gemm_kernel(
    const ushort* __restrict__ A, const ushort* __restrict__ BT,
    const float* __restrict__ bias, void* __restrict__ Cout,
    const void* __restrict__ extra, int M, int N, int K, int nbn, int cpx) {
  __shared__ ushort SH[24576];   // A: 3x4096, B: 3x4096 (ushorts); epi scratch reuse
  const int tid = threadIdx.x;
  const int flat = blockIdx.x;
  const int wg = (flat & 7) * cpx + (flat >> 3);   // bijective XCD swizzle (nwg%8==0)
  const int bm = wg / nbn, bn = wg - bm * nbn;
  const int m0 = bm * 128, n0 = bn * 128;
  const int lane = tid & 63, wave = tid >> 6;      // 8 waves
  const int wr = (wave >> 2) * 64, wc = (wave & 3) * 32;
  const int fr = lane & 15, fq = lane >> 4;
  const int key = (fr >> 1) & 3;                   // read-side swizzle key (lane-const)
  f32x4 acc[4][2] = {};

  // staging: wave stages A rows [wave*16,+16) and B rows [wave*16,+16); 1 DMA each.
  // LDS slot s of row r holds global k-slot s ^ ((r>>1)&3); source pre-swizzled.
  const int r8 = lane >> 2;                        // 0..15 row within 16-row chunk
  const int sslot = ((lane & 3) ^ ((lane >> 3) & 3)) * 8;   // swizzled source col
  const size_t a_base = (size_t)(m0 + wave * 16 + r8) * K + sslot;
  const size_t b_base = (size_t)(n0 + wave * 16 + r8) * K + sslot;

#define STAGE(c, kt_) do {                                        \
    gload_lds16(A  + a_base + (kt_), SH + (c) * 4096 + wave * 512);          \
    gload_lds16(BT + b_base + (kt_), SH + 12288 + (c) * 4096 + wave * 512);  \
  } while (0)

  const int NT = K >> 5;   // 12 for K=384
  STAGE(0, 0);
  STAGE(1, 32);
  asm volatile("s_waitcnt vmcnt(2) lgkmcnt(0)" ::: "memory");
  __builtin_amdgcn_s_barrier();
  __builtin_amdgcn_sched_barrier(0);

  int cur = 0;
  for (int t = 0; t < NT; ++t) {
    if (t + 2 < NT) {
      int nx = cur + 2; if (nx >= 3) nx -= 3;
      STAGE(nx, (t + 2) * 32);
    }
    bf16x8 a[4], b[2];
#pragma unroll
    for (int i = 0; i < 4; i++) {
      int ra = wr + i * 16 + fr;
      a[i] = *(const bf16x8*)&SH[cur * 4096 + ra * 32 + ((fq ^ key) * 8)];
    }
#pragma unroll
    for (int j = 0; j < 2; j++) {
      int rb = wc + j * 16 + fr;
      b[j] = *(const bf16x8*)&SH[12288 + cur * 4096 + rb * 32 + ((fq ^ key) * 8)];
    }
#pragma unroll
    for (int i = 0; i < 4; i++)
#pragma unroll
      for (int j = 0; j < 2; j++)
        acc[i][j] = __builtin_amdgcn_mfma_f32_16x16x32_bf16(a[i], b[j], acc[i][j], 0, 0, 0);
    if (t + 1 < NT) {
      if (t + 2 < NT) asm volatile("s_waitcnt vmcnt(2) lgkmcnt(0)" ::: "memory");
      else            asm volatile("s_waitcnt vmcnt(0) lgkmcnt(0)" ::: "memory");
      __builtin_amdgcn_s_barrier();
      __builtin_amdgcn_sched_barrier(0);
      cur += 1; if (cur >= 3) cur -= 3;
    }
  }
#undef STAGE

  // -------- epilogue: acc -> per-wave LDS scratch -> coalesced wide stores --------
  __syncthreads();   // all waves done with staging buffers
  float biasv[2];
#pragma unroll
  for (int j = 0; j < 2; j++) biasv[j] = bias[n0 + wc + j * 16 + fr];

  if constexpr (EPI == EPI_MLP2) {
    // fp32 out + bf16 residual; 2 chunks of 32 rows; scratch [32][36] f32 per wave
    float* scr = (float*)SH + wave * 1152;
#pragma unroll
    for (int c = 0; c < 2; c++) {
#pragma unroll
      for (int i = 0; i < 2; i++)
#pragma unroll
        for (int j = 0; j < 2; j++)
#pragma unroll
          for (int r = 0; r < 4; r++)
            scr[(i * 16 + fq * 4 + r) * 36 + j * 16 + fr] = acc[c * 2 + i][j][r] + biasv[j];
      asm volatile("" ::: "memory");
#pragma unroll
      for (int it = 0; it < 4; it++) {
        int row = it * 8 + (lane >> 3);
        f32x4 v = *(const f32x4*)&scr[row * 36 + (lane & 7) * 4];
        int m = m0 + wr + c * 32 + row;
        int col0 = n0 + wc + (lane & 7) * 4;
        ushort4 xv = *(const ushort4*)((const ushort*)extra + (size_t)m * N + col0);
        v[0] += bf2f(xv.x); v[1] += bf2f(xv.y); v[2] += bf2f(xv.z); v[3] += bf2f(xv.w);
        *(f32x4*)((float*)Cout + (size_t)m * N + col0) = v;
      }
      asm volatile("" ::: "memory");
    }
  } else {
    // bf16 out; scratch [64][36] ushort per wave
    ushort* scr = SH + wave * 2304;
#pragma unroll
    for (int i = 0; i < 4; i++)
#pragma unroll
      for (int j = 0; j < 2; j++)
#pragma unroll
        for (int r = 0; r < 4; r++) {
          float val = acc[i][j][r] + biasv[j];
          if constexpr (EPI == EPI_MLP1) val = gelu_fast(val);
          scr[(i * 16 + fq * 4 + r) * 36 + j * 16 + fr] = f2bf(val);
        }
    asm volatile("" ::: "memory");
#pragma unroll
    for (int it = 0; it < 4; it++) {
      int row = it * 16 + (lane >> 2);
      int m = m0 + wr + row;
      int col0 = n0 + wc + (lane & 3) * 8;
      ushort v[8];
      *(bf16x8*)v = *(const bf16x8*)&scr[row * 36 + (lane & 3) * 8];
      if constexpr (EPI == EPI_PROJ) {
        int b_ = m / 3136, rem = m - b_ * 3136;
        int win = rem / 49, nn = rem - win * 49;
        int wh = win >> 3, ww = win & 7;
        int ii = nn / 7, jj = nn - (nn / 7) * 7;
        int h = wh * 7 + ii + 3; if (h >= 56) h -= 56;
        int w = ww * 7 + jj + 3; if (w >= 56) w -= 56;
        size_t rowbase = ((size_t)b_ * 3136 + h * 56 + w) * 384;
        const float* e = (const float*)extra + rowbase + col0;
        ushort o[8];
#pragma unroll
        for (int k = 0; k < 8; k++) o[k] = f2bf(bf2f(v[k]) + e[k]);
        *(bf16x8*)((ushort*)Cout + rowbase + col0) = *(bf16x8*)o;
      } else {
        *(bf16x8*)((ushort*)Cout + (size_t)m * N + col0) = *(bf16x8*)v;
      }
    }
  }
}

// ---------------- windowed attention: streaming softmax, f16 dot2 math ----------------
__global__ __launch_bounds__(128) void attn_kernel(
    const ushort* __restrict__ qkv, const float* __restrict__ bias_table,
    ushort* __restrict__ outp) {
  __shared__ unsigned k_lds[2][49][16];
  __shared__ unsigned v_lds[2][32][28];
  __shared__ float btab[2][169];
  __shared__ char  rgn[2][52];
  const int wave = threadIdx.x >> 6, lane = threadIdx.x & 63;
  const int gw = blockIdx.x * 2 + wave;        // 0..24575
  const int bw = gw / 12, head = gw - bw * 12;
  const ushort* base = qkv + (size_t)bw * 49 * 1152 + head * 32;

  for (int t = lane; t < 392; t += 64) {
    int m = t >> 3, c4 = t & 7;
    ushort4 u = *(const ushort4*)(base + (size_t)m * 1152 + 384 + c4 * 4);
    *(uint2*)&k_lds[wave][m][c4 * 2] =
        make_uint2(pkrtz(bf2f(u.x), bf2f(u.y)), pkrtz(bf2f(u.z), bf2f(u.w)));
  }
  for (int t = lane; t < 224; t += 64) {
    int m2 = t >> 3, c4 = t & 7;
    float4 f0 = make_float4(0.f, 0.f, 0.f, 0.f), f1 = f0;
    if (m2 <= 24) {
      ushort4 u = *(const ushort4*)(base + (size_t)(2 * m2) * 1152 + 768 + c4 * 4);
      f0 = make_float4(bf2f(u.x), bf2f(u.y), bf2f(u.z), bf2f(u.w));
    }
    if (m2 <= 23) {
      ushort4 u = *(const ushort4*)(base + (size_t)(2 * m2 + 1) * 1152 + 768 + c4 * 4);
      f1 = make_float4(bf2f(u.x), bf2f(u.y), bf2f(u.z), bf2f(u.w));
    }
    v_lds[wave][c4 * 4 + 0][m2] = pkrtz(f0.x, f1.x);
    v_lds[wave][c4 * 4 + 1][m2] = pkrtz(f0.y, f1.y);
    v_lds[wave][c4 * 4 + 2][m2] = pkrtz(f0.z, f1.z);
    v_lds[wave][c4 * 4 + 3][m2] = pkrtz(f0.w, f1.w);
  }
  for (int t = lane; t < 169; t += 64) btab[wave][t] = bias_table[t * 12 + head];
  {
    int win = bw & 63, wh = win >> 3, ww = win & 7;
    if (lane < 49) {
      int i = lane / 7, j = lane - (lane / 7) * 7;
      int hs = wh * 7 + i, wsf = ww * 7 + j;
      int bh = (hs < 49) ? 0 : (hs < 53 ? 1 : 2);
      int bv = (wsf < 49) ? 0 : (wsf < 53 ? 1 : 2);
      rgn[wave][lane] = (char)(bh * 3 + bv);
    }
  }
  __syncthreads();

  const int n = (lane < 49) ? lane : 48;
  unsigned q2[16];
  {
    const ushort* qp = base + (size_t)n * 1152;
#pragma unroll
    for (int t = 0; t < 8; t++) {
      ushort4 u = *(const ushort4*)(qp + t * 4);
      const float sc = 0.17677669529663689f;
      q2[2 * t]     = pkrtz(bf2f(u.x) * sc, bf2f(u.y) * sc);
      q2[2 * t + 1] = pkrtz(bf2f(u.z) * sc, bf2f(u.w) * sc);
    }
  }
  const char rn = rgn[wave][n];
  const int i_n = n / 7, j_n = n - (n / 7) * 7;
  const float* bt = &btab[wave][(i_n + 6) * 13 + (j_n + 6)];

  auto qk_one = [&](int m) -> float {
    const uint4* kr = (const uint4*)&k_lds[wave][m][0];
    uint4 k0 = kr[0], k1 = kr[1], k2 = kr[2], k3 = kr[3];
    float a0 = 0.f, a1 = 0.f, a2 = 0.f, a3 = 0.f;
    a0 = fdot2(k0.x, q2[0],  a0); a1 = fdot2(k0.y, q2[1],  a1);
    a2 = fdot2(k0.z, q2[2],  a2); a3 = fdot2(k0.w, q2[3],  a3);
    a0 = fdot2(k1.x, q2[4],  a0); a1 = fdot2(k1.y, q2[5],  a1);
    a2 = fdot2(k1.z, q2[6],  a2); a3 = fdot2(k1.w, q2[7],  a3);
    a0 = fdot2(k2.x, q2[8],  a0); a1 = fdot2(k2.y, q2[9],  a1);
    a2 = fdot2(k2.z, q2[10], a2); a3 = fdot2(k2.w, q2[11], a3);
    a0 = fdot2(k3.x, q2[12], a0); a1 = fdot2(k3.y, q2[13], a1);
    a2 = fdot2(k3.z, q2[14], a2); a3 = fdot2(k3.w, q2[15], a3);
    int im = m / 7, jm = m - (m / 7) * 7;
    float s = (a0 + a1) + (a2 + a3) + bt[-im * 13 - jm];
    s += (rgn[wave][m] == rn) ? 0.f : -100.f;
    return __expf(s);
  };

  float sum = 0.f;
  unsigned p2[28];
#pragma unroll
  for (int m2 = 0; m2 < 25; m2++) {
    float eA = qk_one(2 * m2);
    float eB = (m2 < 24) ? qk_one(2 * m2 + 1) : 0.f;
    sum += eA + eB;
    p2[m2] = pkrtz(eA, eB);
  }
  p2[25] = 0; p2[26] = 0; p2[27] = 0;

  const float invs = __builtin_amdgcn_rcpf(sum);
  ushort* op = outp + (size_t)(bw * 49 + n) * 384 + head * 32;
#pragma unroll
  for (int dc = 0; dc < 4; dc++) {
    ushort u8[8];
#pragma unroll
    for (int j = 0; j < 8; j++) {
      const uint4* vr = (const uint4*)&v_lds[wave][dc * 8 + j][0];
      float a0 = 0.f, a1 = 0.f, a2 = 0.f, a3 = 0.f;
#pragma unroll
      for (int t7 = 0; t7 < 7; t7++) {
        uint4 vv = vr[t7];
        a0 = fdot2(vv.x, p2[t7 * 4 + 0], a0);
        a1 = fdot2(vv.y, p2[t7 * 4 + 1], a1);
        a2 = fdot2(vv.z, p2[t7 * 4 + 2], a2);
        a3 = fdot2(vv.w, p2[t7 * 4 + 3], a3);
      }
      u8[j] = f2bf(((a0 + a1) + (a2 + a3)) * invs);
    }
    if (lane < 49) *(bf16x8*)(op + dc * 8) = *(bf16x8*)u8;
  }
}

extern "C" void kernel_launch(void* const* d_in, const int* in_sizes, int n_in,
                              void* d_out, int out_size, void* d_ws, size_t ws_size,
                              hipStream_t stream) {
  (void)in_sizes; (void)n_in; (void)out_size; (void)ws_size;
  const float* x      = (const float*)d_in[0];
  const float* W_qkv  = (const float*)d_in[1];
  const float* b_qkv  = (const float*)d_in[2];
  const float* W_proj = (const float*)d_in[3];
  const float* b_proj = (const float*)d_in[4];
  const float* btab   = (const float*)d_in[5];
  const float* gamma1 = (const float*)d_in[6];
  const float* beta1  = (const float*)d_in[7];
  const float* gamma2 = (const float*)d_in[8];
  const float* beta2  = (const float*)d_in[9];
  const float* W_mlp1 = (const float*)d_in[10];
  const float* b_mlp1 = (const float*)d_in[11];
  const float* W_mlp2 = (const float*)d_in[12];
  const float* b_mlp2 = (const float*)d_in[13];

  const int M = 100352;  // 32 * 3136 token rows

  char* ws = (char*)d_ws;
  ushort* WqkvT  = (ushort*)ws; ws += (size_t)1152 * 384 * 2;
  ushort* WprojT = (ushort*)ws; ws += (size_t)384 * 384 * 2;
  ushort* Wm1T   = (ushort*)ws; ws += (size_t)1536 * 384 * 2;
  ushort* Wm2T   = (ushort*)ws; ws += (size_t)384 * 1536 * 2;
  ushort* x1     = (ushort*)ws; ws += (size_t)M * 384 * 2;   // bf16 residual trunk
  ushort* h2     = (ushort*)ws; ws += (size_t)M * 384 * 2;
  ushort* bufB   = (ushort*)ws;                               // overlay region
  ushort* xw     = bufB;                                      // [M][384]
  ushort* qkv    = bufB + (size_t)M * 384;                    // [M][1152]
  ushort* attn_o = bufB;                                      // [M][384]  (over xw)
  ushort* g      = bufB;                                      // [M][1536] (over all)

  wtrans_kernel<<<(384 * 1152 + 255) / 256, 256, 0, stream>>>(W_qkv,  WqkvT,  384, 1152);
  wtrans_kernel<<<(384 * 384  + 255) / 256, 256, 0, stream>>>(W_proj, WprojT, 384, 384);
  wtrans_kernel<<<(384 * 1536 + 255) / 256, 256, 0, stream>>>(W_mlp1, Wm1T,   384, 1536);
  wtrans_kernel<<<(1536 * 384 + 255) / 256, 256, 0, stream>>>(W_mlp2, Wm2T,   1536, 384);

  ln_kernel<true,  false><<<M / 4, 256, 0, stream>>>(x, xw, gamma1, beta1);

  {
    int nbn = 1152 / 128, nwg = (M / 128) * nbn;
    gemm_kernel<EPI_QKV ><<<nwg, 512, 0, stream>>>(xw, WqkvT, b_qkv, qkv, nullptr, M, 1152, 384, nbn, nwg / 8);
  }
  attn_kernel<<<12288, 128, 0, stream>>>(qkv, btab, attn_o);
  {
    int nbn = 384 / 128, nwg = (M / 128) * nbn;
    gemm_kernel<EPI_PROJ><<<nwg, 512, 0, stream>>>(attn_o, WprojT, b_proj, x1, x, M, 384, 384, nbn, nwg / 8);
  }
  ln_kernel<false, true><<<M / 4, 256, 0, stream>>>(x1, h2, gamma2, beta2);
  {
    int nbn = 1536 / 128, nwg = (M / 128) * nbn;
    gemm_kernel<EPI_MLP1><<<nwg, 512, 0, stream>>>(h2, Wm1T, b_mlp1, g, nullptr, M, 1536, 384, nbn, nwg / 8);
  }
  {
    int nbn = 384 / 128, nwg = (M / 128) * nbn;
    gemm_kernel<EPI_MLP2><<<nwg, 512, 0, stream>>>(g, Wm2T, b_mlp2, d_out, x1, M, 384, 1536, nbn, nwg / 8);
  }
}

// Round 11
// 847.092 us; speedup vs baseline: 1.2912x; 1.0256x over previous
//
#include <hip/hip_runtime.h>
#include <math.h>

typedef __bf16 bf16x8 __attribute__((ext_vector_type(8)));
typedef float  f32x4  __attribute__((ext_vector_type(4)));
typedef _Float16 f16x2 __attribute__((ext_vector_type(2)));

__device__ __forceinline__ ushort f2bf(float f) {
  union { float f; unsigned u; } v; v.f = f;
  unsigned r = v.u + 0x7FFFu + ((v.u >> 16) & 1u);
  return (ushort)(r >> 16);
}
__device__ __forceinline__ float bf2f(ushort s) {
  union { unsigned u; float f; } v; v.u = ((unsigned)s) << 16;
  return v.f;
}
__device__ __forceinline__ unsigned pkrtz(float a, float b) {
  return __builtin_bit_cast(unsigned, __builtin_amdgcn_cvt_pkrtz(a, b));
}
__device__ __forceinline__ float fdot2(unsigned a, unsigned b, float c) {
  return __builtin_amdgcn_fdot2(__builtin_bit_cast(f16x2, a),
                                __builtin_bit_cast(f16x2, b), c, false);
}

__device__ __forceinline__ void gload_lds16(const ushort* g, ushort* l) {
  __builtin_amdgcn_global_load_lds((const __attribute__((address_space(1))) void*)g,
                                   (__attribute__((address_space(3))) void*)l, 16, 0, 0);
}

// fast GELU: h * sigmoid(1.5957691*h*(1+0.044715*h^2)), sigmoid via v_rcp
__device__ __forceinline__ float gelu_fast(float h) {
  float y = 1.5957691216057308f * h * (1.f + 0.044715f * h * h);
  return h * __builtin_amdgcn_rcpf(1.f + __expf(-y));
}

// ---------------- weight transpose + bf16 convert: W[K][N] -> WT[N][K] ----------------
__global__ void wtrans_kernel(const float* __restrict__ W, ushort* __restrict__ WT,
                              int K, int N) {
  int idx = blockIdx.x * 256 + threadIdx.x;
  if (idx >= K * N) return;
  int n = idx / K, k = idx - n * K;
  WT[idx] = f2bf(W[(size_t)k * N + n]);
}

// ---------------- LayerNorm (one wave per row of 384) ----------------
template<bool SHIFT, bool INBF16>
__global__ __launch_bounds__(256) void ln_kernel(const void* __restrict__ inp,
                                                 ushort* __restrict__ outp,
                                                 const float* __restrict__ gamma,
                                                 const float* __restrict__ beta) {
  const int lane = threadIdx.x & 63;
  const int row = blockIdx.x * 4 + (threadIdx.x >> 6);
  size_t src;
  if (SHIFT) {
    int b = row / 3136, rem = row - b * 3136;
    int win = rem / 49, n = rem - win * 49;
    int wh = win >> 3, ww = win & 7;
    int i = n / 7, j = n - (n / 7) * 7;
    int h = wh * 7 + i + 3; if (h >= 56) h -= 56;
    int w = ww * 7 + j + 3; if (w >= 56) w -= 56;
    src = ((size_t)b * 3136 + h * 56 + w) * 384;
  } else {
    src = (size_t)row * 384;
  }
  float xv[6];
  float sum = 0.f, sq = 0.f;
#pragma unroll
  for (int t = 0; t < 6; t++) {
    int c = lane + t * 64;
    float f;
    if (INBF16) f = bf2f(((const ushort*)inp)[src + c]);
    else        f = ((const float*)inp)[src + c];
    xv[t] = f; sum += f; sq += f * f;
  }
#pragma unroll
  for (int o = 32; o; o >>= 1) { sum += __shfl_xor(sum, o); sq += __shfl_xor(sq, o); }
  float mean = sum * (1.f / 384.f);
  float var  = sq * (1.f / 384.f) - mean * mean;
  float inv  = rsqrtf(var + 1e-5f);
#pragma unroll
  for (int t = 0; t < 6; t++) {
    int c = lane + t * 64;
    outp[(size_t)row * 384 + c] = f2bf((xv[t] - mean) * inv * gamma[c] + beta[c]);
  }
}

// ---------------- bf16 MFMA GEMM: C[M][N] = A[M][K] * BT[N][K]^T + bias ----------------
// 256x128 block, 8 waves x (64x64 wave tile), BK=32, 3-buffer LDS (72KB -> 2 blocks/CU),
// 2-deep prefetch, counted vmcnt(3), raw s_barrier, XOR-swizzle key (row>>1)&3,
// vectorized epilogue via per-wave LDS scratch.
#define EPI_QKV  0
#define EPI_PROJ 1
#define EPI_MLP1 2
#define EPI_MLP2 3

template<int EPI>
__global__ __launch_bounds__(512, 4) void gemm_kernel(
    const ushort* __restrict__ A, const ushort* __restrict__ BT,
    const float* __restrict__ bias, void* __restrict__ Cout,
    const void* __restrict__ extra, int M, int N, int K, int nbn, int cpx) {
  __shared__ ushort SH[36864];   // A: 3x8192, B (at 24576): 3x4096; epi scratch reuse
  const int tid = threadIdx.x;
  const int flat = blockIdx.x;
  const int wg = (flat & 7) * cpx + (flat >> 3);   // bijective XCD swizzle (nwg%8==0)
  const int bm = wg / nbn, bn = wg - bm * nbn;
  const int m0 = bm * 256, n0 = bn * 128;
  const int lane = tid & 63, wave = tid >> 6;      // 8 waves
  const int wr = (wave >> 1) * 64, wc = (wave & 1) * 64;
  const int fr = lane & 15, fq = lane >> 4;
  const int key = (fr >> 1) & 3;                   // read-side swizzle key (lane-const)
  f32x4 acc[4][4] = {};

  // staging: wave stages A rows [wave*32,+32) (2 DMAs) and B rows [wave*16,+16) (1 DMA).
  // LDS slot s of row r holds global k-slot s ^ ((r>>1)&3); source pre-swizzled.
  const int r16 = lane >> 2;                       // 0..15 row within 16-row chunk
  const int sslot = ((lane & 3) ^ ((lane >> 3) & 3)) * 8;   // swizzled source col
  const size_t a_base = (size_t)(m0 + wave * 32 + r16) * K + sslot;
  const size_t b_base = (size_t)(n0 + wave * 16 + r16) * K + sslot;

#define STAGE(c, kt_) do {                                                     \
    gload_lds16(A  + a_base + (kt_),          SH + (c) * 8192 + wave * 1024);  \
    gload_lds16(A  + a_base + 16 * K + (kt_), SH + (c) * 8192 + wave * 1024 + 512); \
    gload_lds16(BT + b_base + (kt_),          SH + 24576 + (c) * 4096 + wave * 512); \
  } while (0)

  const int NT = K >> 5;   // 12 (K=384) or 48 (K=1536)
  STAGE(0, 0);
  STAGE(1, 32);
  asm volatile("s_waitcnt vmcnt(3) lgkmcnt(0)" ::: "memory");
  __builtin_amdgcn_s_barrier();
  __builtin_amdgcn_sched_barrier(0);

  int cur = 0;
  for (int t = 0; t < NT; ++t) {
    if (t + 2 < NT) {
      int nx = cur + 2; if (nx >= 3) nx -= 3;
      STAGE(nx, (t + 2) * 32);
    }
    bf16x8 a[4], b[4];
#pragma unroll
    for (int i = 0; i < 4; i++) {
      int ra = wr + i * 16 + fr;
      a[i] = *(const bf16x8*)&SH[cur * 8192 + ra * 32 + ((fq ^ key) * 8)];
    }
#pragma unroll
    for (int j = 0; j < 4; j++) {
      int rb = wc + j * 16 + fr;
      b[j] = *(const bf16x8*)&SH[24576 + cur * 4096 + rb * 32 + ((fq ^ key) * 8)];
    }
#pragma unroll
    for (int i = 0; i < 4; i++)
#pragma unroll
      for (int j = 0; j < 4; j++)
        acc[i][j] = __builtin_amdgcn_mfma_f32_16x16x32_bf16(a[i], b[j], acc[i][j], 0, 0, 0);
    if (t + 1 < NT) {
      if (t + 2 < NT) asm volatile("s_waitcnt vmcnt(3) lgkmcnt(0)" ::: "memory");
      else            asm volatile("s_waitcnt vmcnt(0) lgkmcnt(0)" ::: "memory");
      __builtin_amdgcn_s_barrier();
      __builtin_amdgcn_sched_barrier(0);
      cur += 1; if (cur >= 3) cur -= 3;
    }
  }
#undef STAGE

  // -------- epilogue: acc -> per-wave LDS scratch -> coalesced wide stores --------
  __syncthreads();   // all waves done with staging buffers
  float biasv[4];
#pragma unroll
  for (int j = 0; j < 4; j++) biasv[j] = bias[n0 + wc + j * 16 + fr];

  if constexpr (EPI == EPI_MLP2) {
    // fp32 out + bf16 residual; 2 chunks of 32 rows; scratch [32][66] f32 per wave
    float* scr = (float*)SH + wave * 2112;
#pragma unroll
    for (int c = 0; c < 2; c++) {
#pragma unroll
      for (int i = 0; i < 2; i++)
#pragma unroll
        for (int j = 0; j < 4; j++)
#pragma unroll
          for (int r = 0; r < 4; r++)
            scr[(i * 16 + fq * 4 + r) * 66 + j * 16 + fr] = acc[c * 2 + i][j][r] + biasv[j];
      asm volatile("" ::: "memory");
#pragma unroll
      for (int it = 0; it < 8; it++) {
        int row = it * 4 + (lane >> 4);
        f32x4 v = *(const f32x4*)&scr[row * 66 + (lane & 15) * 4];
        int m = m0 + wr + c * 32 + row;
        int col0 = n0 + wc + (lane & 15) * 4;
        ushort4 xv = *(const ushort4*)((const ushort*)extra + (size_t)m * N + col0);
        v[0] += bf2f(xv.x); v[1] += bf2f(xv.y); v[2] += bf2f(xv.z); v[3] += bf2f(xv.w);
        *(f32x4*)((float*)Cout + (size_t)m * N + col0) = v;
      }
      asm volatile("" ::: "memory");
    }
  } else {
    // bf16 out; scratch [64][68] ushort per wave
    ushort* scr = SH + wave * 4352;
#pragma unroll
    for (int i = 0; i < 4; i++)
#pragma unroll
      for (int j = 0; j < 4; j++)
#pragma unroll
        for (int r = 0; r < 4; r++) {
          float val = acc[i][j][r] + biasv[j];
          if constexpr (EPI == EPI_MLP1) val = gelu_fast(val);
          scr[(i * 16 + fq * 4 + r) * 68 + j * 16 + fr] = f2bf(val);
        }
    asm volatile("" ::: "memory");
#pragma unroll
    for (int it = 0; it < 8; it++) {
      int row = it * 8 + (lane >> 3);
      int m = m0 + wr + row;
      int col0 = n0 + wc + (lane & 7) * 8;
      ushort v[8];
      *(bf16x8*)v = *(const bf16x8*)&scr[row * 68 + (lane & 7) * 8];
      if constexpr (EPI == EPI_PROJ) {
        int b_ = m / 3136, rem = m - b_ * 3136;
        int win = rem / 49, nn = rem - win * 49;
        int wh = win >> 3, ww = win & 7;
        int ii = nn / 7, jj = nn - (nn / 7) * 7;
        int h = wh * 7 + ii + 3; if (h >= 56) h -= 56;
        int w = ww * 7 + jj + 3; if (w >= 56) w -= 56;
        size_t rowbase = ((size_t)b_ * 3136 + h * 56 + w) * 384;
        const float* e = (const float*)extra + rowbase + col0;
        ushort o[8];
#pragma unroll
        for (int k = 0; k < 8; k++) o[k] = f2bf(bf2f(v[k]) + e[k]);
        *(bf16x8*)((ushort*)Cout + rowbase + col0) = *(bf16x8*)o;
      } else {
        *(bf16x8*)((ushort*)Cout + (size_t)m * N + col0) = *(bf16x8*)v;
      }
    }
  }
}

// ---------------- windowed attention: streaming softmax, f16 dot2 math ----------------
__global__ __launch_bounds__(128) void attn_kernel(
    const ushort* __restrict__ qkv, const float* __restrict__ bias_table,
    ushort* __restrict__ outp) {
  __shared__ unsigned k_lds[2][49][16];
  __shared__ unsigned v_lds[2][32][28];
  __shared__ float btab[2][169];
  __shared__ char  rgn[2][52];
  const int wave = threadIdx.x >> 6, lane = threadIdx.x & 63;
  const int gw = blockIdx.x * 2 + wave;        // 0..24575
  const int bw = gw / 12, head = gw - bw * 12;
  const ushort* base = qkv + (size_t)bw * 49 * 1152 + head * 32;

  for (int t = lane; t < 392; t += 64) {
    int m = t >> 3, c4 = t & 7;
    ushort4 u = *(const ushort4*)(base + (size_t)m * 1152 + 384 + c4 * 4);
    *(uint2*)&k_lds[wave][m][c4 * 2] =
        make_uint2(pkrtz(bf2f(u.x), bf2f(u.y)), pkrtz(bf2f(u.z), bf2f(u.w)));
  }
  for (int t = lane; t < 224; t += 64) {
    int m2 = t >> 3, c4 = t & 7;
    float4 f0 = make_float4(0.f, 0.f, 0.f, 0.f), f1 = f0;
    if (m2 <= 24) {
      ushort4 u = *(const ushort4*)(base + (size_t)(2 * m2) * 1152 + 768 + c4 * 4);
      f0 = make_float4(bf2f(u.x), bf2f(u.y), bf2f(u.z), bf2f(u.w));
    }
    if (m2 <= 23) {
      ushort4 u = *(const ushort4*)(base + (size_t)(2 * m2 + 1) * 1152 + 768 + c4 * 4);
      f1 = make_float4(bf2f(u.x), bf2f(u.y), bf2f(u.z), bf2f(u.w));
    }
    v_lds[wave][c4 * 4 + 0][m2] = pkrtz(f0.x, f1.x);
    v_lds[wave][c4 * 4 + 1][m2] = pkrtz(f0.y, f1.y);
    v_lds[wave][c4 * 4 + 2][m2] = pkrtz(f0.z, f1.z);
    v_lds[wave][c4 * 4 + 3][m2] = pkrtz(f0.w, f1.w);
  }
  for (int t = lane; t < 169; t += 64) btab[wave][t] = bias_table[t * 12 + head];
  {
    int win = bw & 63, wh = win >> 3, ww = win & 7;
    if (lane < 49) {
      int i = lane / 7, j = lane - (lane / 7) * 7;
      int hs = wh * 7 + i, wsf = ww * 7 + j;
      int bh = (hs < 49) ? 0 : (hs < 53 ? 1 : 2);
      int bv = (wsf < 49) ? 0 : (wsf < 53 ? 1 : 2);
      rgn[wave][lane] = (char)(bh * 3 + bv);
    }
  }
  __syncthreads();

  const int n = (lane < 49) ? lane : 48;
  unsigned q2[16];
  {
    const ushort* qp = base + (size_t)n * 1152;
#pragma unroll
    for (int t = 0; t < 8; t++) {
      ushort4 u = *(const ushort4*)(qp + t * 4);
      const float sc = 0.17677669529663689f;
      q2[2 * t]     = pkrtz(bf2f(u.x) * sc, bf2f(u.y) * sc);
      q2[2 * t + 1] = pkrtz(bf2f(u.z) * sc, bf2f(u.w) * sc);
    }
  }
  const char rn = rgn[wave][n];
  const int i_n = n / 7, j_n = n - (n / 7) * 7;
  const float* bt = &btab[wave][(i_n + 6) * 13 + (j_n + 6)];

  auto qk_one = [&](int m) -> float {
    const uint4* kr = (const uint4*)&k_lds[wave][m][0];
    uint4 k0 = kr[0], k1 = kr[1], k2 = kr[2], k3 = kr[3];
    float a0 = 0.f, a1 = 0.f, a2 = 0.f, a3 = 0.f;
    a0 = fdot2(k0.x, q2[0],  a0); a1 = fdot2(k0.y, q2[1],  a1);
    a2 = fdot2(k0.z, q2[2],  a2); a3 = fdot2(k0.w, q2[3],  a3);
    a0 = fdot2(k1.x, q2[4],  a0); a1 = fdot2(k1.y, q2[5],  a1);
    a2 = fdot2(k1.z, q2[6],  a2); a3 = fdot2(k1.w, q2[7],  a3);
    a0 = fdot2(k2.x, q2[8],  a0); a1 = fdot2(k2.y, q2[9],  a1);
    a2 = fdot2(k2.z, q2[10], a2); a3 = fdot2(k2.w, q2[11], a3);
    a0 = fdot2(k3.x, q2[12], a0); a1 = fdot2(k3.y, q2[13], a1);
    a2 = fdot2(k3.z, q2[14], a2); a3 = fdot2(k3.w, q2[15], a3);
    int im = m / 7, jm = m - (m / 7) * 7;
    float s = (a0 + a1) + (a2 + a3) + bt[-im * 13 - jm];
    s += (rgn[wave][m] == rn) ? 0.f : -100.f;
    return __expf(s);
  };

  float sum = 0.f;
  unsigned p2[28];
#pragma unroll
  for (int m2 = 0; m2 < 25; m2++) {
    float eA = qk_one(2 * m2);
    float eB = (m2 < 24) ? qk_one(2 * m2 + 1) : 0.f;
    sum += eA + eB;
    p2[m2] = pkrtz(eA, eB);
  }
  p2[25] = 0; p2[26] = 0; p2[27] = 0;

  const float invs = __builtin_amdgcn_rcpf(sum);
  ushort* op = outp + (size_t)(bw * 49 + n) * 384 + head * 32;
#pragma unroll
  for (int dc = 0; dc < 4; dc++) {
    ushort u8[8];
#pragma unroll
    for (int j = 0; j < 8; j++) {
      const uint4* vr = (const uint4*)&v_lds[wave][dc * 8 + j][0];
      float a0 = 0.f, a1 = 0.f, a2 = 0.f, a3 = 0.f;
#pragma unroll
      for (int t7 = 0; t7 < 7; t7++) {
        uint4 vv = vr[t7];
        a0 = fdot2(vv.x, p2[t7 * 4 + 0], a0);
        a1 = fdot2(vv.y, p2[t7 * 4 + 1], a1);
        a2 = fdot2(vv.z, p2[t7 * 4 + 2], a2);
        a3 = fdot2(vv.w, p2[t7 * 4 + 3], a3);
      }
      u8[j] = f2bf(((a0 + a1) + (a2 + a3)) * invs);
    }
    if (lane < 49) *(bf16x8*)(op + dc * 8) = *(bf16x8*)u8;
  }
}

extern "C" void kernel_launch(void* const* d_in, const int* in_sizes, int n_in,
                              void* d_out, int out_size, void* d_ws, size_t ws_size,
                              hipStream_t stream) {
  (void)in_sizes; (void)n_in; (void)out_size; (void)ws_size;
  const float* x      = (const float*)d_in[0];
  const float* W_qkv  = (const float*)d_in[1];
  const float* b_qkv  = (const float*)d_in[2];
  const float* W_proj = (const float*)d_in[3];
  const float* b_proj = (const float*)d_in[4];
  const float* btab   = (const float*)d_in[5];
  const float* gamma1 = (const float*)d_in[6];
  const float* beta1  = (const float*)d_in[7];
  const float* gamma2 = (const float*)d_in[8];
  const float* beta2  = (const float*)d_in[9];
  const float* W_mlp1 = (const float*)d_in[10];
  const float* b_mlp1 = (const float*)d_in[11];
  const float* W_mlp2 = (const float*)d_in[12];
  const float* b_mlp2 = (const float*)d_in[13];

  const int M = 100352;  // 32 * 3136 token rows

  char* ws = (char*)d_ws;
  ushort* WqkvT  = (ushort*)ws; ws += (size_t)1152 * 384 * 2;
  ushort* WprojT = (ushort*)ws; ws += (size_t)384 * 384 * 2;
  ushort* Wm1T   = (ushort*)ws; ws += (size_t)1536 * 384 * 2;
  ushort* Wm2T   = (ushort*)ws; ws += (size_t)384 * 1536 * 2;
  ushort* x1     = (ushort*)ws; ws += (size_t)M * 384 * 2;   // bf16 residual trunk
  ushort* h2     = (ushort*)ws; ws += (size_t)M * 384 * 2;
  ushort* bufB   = (ushort*)ws;                               // overlay region
  ushort* xw     = bufB;                                      // [M][384]
  ushort* qkv    = bufB + (size_t)M * 384;                    // [M][1152]
  ushort* attn_o = bufB;                                      // [M][384]  (over xw)
  ushort* g      = bufB;                                      // [M][1536] (over all)

  wtrans_kernel<<<(384 * 1152 + 255) / 256, 256, 0, stream>>>(W_qkv,  WqkvT,  384, 1152);
  wtrans_kernel<<<(384 * 384  + 255) / 256, 256, 0, stream>>>(W_proj, WprojT, 384, 384);
  wtrans_kernel<<<(384 * 1536 + 255) / 256, 256, 0, stream>>>(W_mlp1, Wm1T,   384, 1536);
  wtrans_kernel<<<(1536 * 384 + 255) / 256, 256, 0, stream>>>(W_mlp2, Wm2T,   1536, 384);

  ln_kernel<true,  false><<<M / 4, 256, 0, stream>>>(x, xw, gamma1, beta1);

  {
    int nbn = 1152 / 128, nwg = (M / 256) * nbn;
    gemm_kernel<EPI_QKV ><<<nwg, 512, 0, stream>>>(xw, WqkvT, b_qkv, qkv, nullptr, M, 1152, 384, nbn, nwg / 8);
  }
  attn_kernel<<<12288, 128, 0, stream>>>(qkv, btab, attn_o);
  {
    int nbn = 384 / 128, nwg = (M / 256) * nbn;
    gemm_kernel<EPI_PROJ><<<nwg, 512, 0, stream>>>(attn_o, WprojT, b_proj, x1, x, M, 384, 384, nbn, nwg / 8);
  }
  ln_kernel<false, true><<<M / 4, 256, 0, stream>>>(x1, h2, gamma2, beta2);
  {
    int nbn = 1536 / 128, nwg = (M / 256) * nbn;
    gemm_kernel<EPI_MLP1><<<nwg, 512, 0, stream>>>(h2, Wm1T, b_mlp1, g, nullptr, M, 1536, 384, nbn, nwg / 8);
  }
  {
    int nbn = 384 / 128, nwg = (M / 256) * nbn;
    gemm_kernel<EPI_MLP2><<<nwg, 512, 0, stream>>>(g, Wm2T, b_mlp2, d_out, x1, M, 384, 1536, nbn, nwg / 8);
  }
}